// Round 3
// baseline (2535.353 us; speedup 1.0000x reference)
//
#include <hip/hip_runtime.h>
#include <cstddef>

// MultiStepLinearRNN: 2-layer linear RNN, T=512 encode + F=32 decode.
// R3: distributed-release grid barrier (32 flag lines), 2-deep register
// prefetch. Plan identical to R2 (matrix Hillis-Steele scan, affine-doubling
// decode). fp16 MFMA (16x16x32), fp32 accum.

typedef _Float16 f16;
typedef _Float16 f16x8 __attribute__((ext_vector_type(8)));
typedef float f32x4 __attribute__((ext_vector_type(4)));

#define GRID 256
#define NCTR 32
#define LDA  136     // LDS row stride in halves (128 + 8 pad)
#define ALPHAF 0.00390625f   // 2^-8 decode state pre-scale
#define RALPHAF 256.0f
#define DIN 128
#define NF 32

// ---------------- workspace layout (units: f16 elements) ----------------
constexpr int SZ = 512*512;
constexpr int off_cat   = 0;                        // [512][640] = A0|Wx0 row-major
constexpr int off_catA1 = off_cat + 512*640;        // [512][1024] = A1|Wx1 row-major
constexpr int off_A0c   = off_catA1 + 512*1024;     // A0 col-major
constexpr int off_A1c   = off_A0c + SZ;             // A1 col-major
constexpr int off_Wpr   = off_A1c + SZ;             // [128][512] Wp row-major
constexpr int off_Wpc   = off_Wpr + 128*512;        // [512][128] Wp col-major
constexpr int off_G0    = off_Wpc + 512*128;        // G rows [1024][1024]: [A0|E ; F10|F11]
constexpr int off_G1    = off_G0 + 512*1024;
constexpr int off_Gc    = off_G1 + 512*1024;        // G col-major [1024][1024]
constexpr int off_A0p   = off_Gc + 1024*1024;       // A0^{2,4,8,16,32} (r,c) pairs
constexpr int off_A1p   = off_A0p + 5*2*SZ;         // A1^{2,4,8,16,32} (r,c) pairs
constexpr int off_Xin   = off_A1p + 5*2*SZ;         // [32768][128] inputs fp16, col=(t*64+b)
constexpr int off_Ga    = off_Xin + 32768*128;      // state buffers [2048][512]; late: GP2 row
constexpr int off_Gb    = off_Ga + 2048*512;        // late: GP2 col
constexpr int off_H0    = off_Gb + 2048*512;        // late: GP8 row
constexpr int off_H1    = off_H0 + 2048*512;        // late: GP8 col
constexpr int off_H2    = off_H1 + 2048*512;        // late: GP16 row
constexpr int off_Ra    = off_H2 + 2048*512;        // late: GP4 row
constexpr int off_Rb    = off_Ra + 2048*512;        // late: GP4 col
constexpr int off_sb    = off_Rb + 2048*512;        // chunk-start states [32 blk][512]
constexpr int off_Fa    = off_sb + 2048*512;        // fold scratch [1024][512]
constexpr int off_Fb    = off_Fa + 1024*512;        // [512][512]
constexpr int off_S     = off_Fb + 512*512;         // decode states [32*64][1024] col-major
constexpr int off_Dc    = off_S + 32*64*1024;       // c replicated [64][1024]
constexpr int off_Db    = off_Dc + 64*1024;         // 4 x [64][1024] b_m buffers
constexpr int off_b0h   = off_Db + 4*64*1024;
constexpr int off_b1h   = off_b0h + 512;
constexpr int off_b0ah  = off_b1h + 512;
constexpr int off_b1ah  = off_b0ah + 512;
constexpr int off_bph   = off_b1ah + 512;
constexpr int off_bpX   = off_bph + 128;            // bp replicated 64 cols [64][128]
constexpr int off_ctr   = off_bpX + 64*128;         // 2048 u32 barrier state
// total ~= 49.3 MB

constexpr int A0pr(int i){ return off_A0p + i*2*SZ; }
constexpr int A0pc(int i){ return off_A0p + i*2*SZ + SZ; }
constexpr int A1pr(int i){ return off_A1p + i*2*SZ; }
constexpr int A1pc(int i){ return off_A1p + i*2*SZ + SZ; }
constexpr int Hoff(int n){ int m = n % 3; return m==0 ? off_H0 : (m==1 ? off_H1 : off_H2); }
constexpr int Rboff(int n){ return (n & 1) ? off_Ra : off_Rb; }
constexpr int GPr(int k){ return k==0?off_G0 : k==1?off_Ga : k==2?off_Ra : k==3?off_H0 : off_H2; }
constexpr int Bb(int k){ return k==0?off_Dc : off_Db + (k-1)*64*1024; }

// ---------------- op table ----------------
struct Op {
  int m_off, m_rstride, rows, cols;
  int k1, x1_off, x1_ks, x1_s1, x1_s2;
  int k2, x2_off, x2_ks, x2_s1, x2_s2;
  int add_off, add_ks, add_s1, add_s2;
  int bias_off; float scale;
  int y_off, y_ks, y_s1, y_s2;
  int yt_off, yt_rstride;
  int out32, tile_base;
};
constexpr int MAXOPS = 96, MAXG = 48;
struct Plan { Op ops[MAXOPS]; int gstart[MAXG+1]; int gtiles[MAXG]; int nops, ng; };

constexpr Op mko() {
  Op o{};
  o.m_off=0; o.m_rstride=512; o.rows=512; o.cols=512;
  o.k1=512; o.x1_off=0; o.x1_ks=512; o.x1_s1=64; o.x1_s2=0;
  o.k2=0; o.x2_off=0; o.x2_ks=128; o.x2_s1=1024; o.x2_s2=0;
  o.add_off=-1; o.add_ks=512; o.add_s1=64; o.add_s2=0;
  o.bias_off=-1; o.scale=1.0f;
  o.y_off=-1; o.y_ks=512; o.y_s1=64; o.y_s2=0;
  o.yt_off=-1; o.yt_rstride=512; o.out32=0; o.tile_base=0;
  return o;
}
constexpr int op_ntiles(const Op& o){ return (o.rows>>7)*(o.cols>>6); }

struct Builder { Plan p{}; int nops=0, ng=0, gtile=0; };
constexpr void push(Builder& b, Op o){ o.tile_base=b.gtile; b.gtile+=op_ntiles(o); b.p.ops[b.nops++]=o; }
constexpr void endg(Builder& b){ b.p.gtiles[b.ng]=b.gtile; b.ng++; b.p.gstart[b.ng]=b.nops; b.gtile=0; }

constexpr Op SQ(int moff,int mrs,int x1,int yc,int yr){
  Op o=mko(); o.m_off=moff; o.m_rstride=mrs; o.x1_off=x1; o.y_off=yc; o.yt_off=yr; return o; }
constexpr Op SQG(int mr,int xc,int yc,int yr){
  Op o=mko(); o.rows=1024; o.cols=1024; o.k1=1024; o.m_off=mr; o.m_rstride=1024;
  o.x1_off=xc; o.x1_ks=1024; o.y_off=yc; o.y_ks=1024; o.yt_off=yr; o.yt_rstride=1024; return o; }
constexpr Op P2op(int s){
  Op o=mko(); o.cols=2048; o.bias_off=off_b0h;
  o.k2=128; o.x2_off=off_Xin; o.x2_s2=(s-1)*64;
  o.y_off=(s&1)?off_Ga:off_Gb;
  if (s==1){ o.m_off=off_cat+512; o.m_rstride=640; o.k1=0; }
  else { o.m_off=off_cat; o.m_rstride=640; o.x1_off=(s&1)?off_Gb:off_Ga; }
  return o; }
constexpr Op P4h(int s){
  Op o=mko(); o.cols=2048; o.bias_off=off_b0h;
  o.m_off=off_cat; o.m_rstride=640;
  o.x1_off=(s==1)?off_sb:Hoff(s-1);
  o.k2=128; o.x2_off=off_Xin; o.x2_s2=(s-1)*64;
  o.y_off=Hoff(s); return o; }
constexpr Op P4rw(int s){
  Op o=mko(); o.cols=2048; o.bias_off=off_b1h;
  o.m_off=off_catA1; o.m_rstride=1024; o.x1_off=Rboff(s-1);
  o.k2=512; o.x2_off=Hoff(s-2); o.x2_ks=512; o.x2_s1=64; o.x2_s2=0;
  o.y_off=Rboff(s); return o; }
constexpr Op FOLD(int pw,int cols,int xoff,int yoff,int yks,float sc){
  Op o=mko(); o.m_off=pw; o.cols=cols; o.x1_off=xoff; o.x1_s1=128;
  o.add_off=xoff; o.add_s1=128; o.add_s2=64; o.y_off=yoff; o.y_ks=yks; o.scale=sc; return o; }
constexpr Op DECA(int k){
  Op o=mko(); int m=1<<k;
  o.rows=1024; o.cols=m*64; o.k1=1024; o.m_off=GPr(k); o.m_rstride=1024;
  o.x1_off=off_S; o.x1_ks=1024; o.bias_off=Bb(k);
  o.y_off=off_S; o.y_ks=1024; o.y_s2=m*64; return o; }
constexpr Op DECB(int k){
  Op o=mko(); o.rows=1024; o.cols=64; o.k1=1024; o.m_off=GPr(k); o.m_rstride=1024;
  o.x1_off=Bb(k); o.x1_ks=1024; o.bias_off=Bb(k);
  o.y_off=Bb(k+1); o.y_ks=1024; return o; }

constexpr Plan build_plan() {
  Builder b{}; b.p.gstart[0]=0;
  // g0: E, A0^2, A1^2, F10, c0, P2 s1
  { Op o=mko(); o.m_off=off_cat+512; o.m_rstride=640; o.k1=128; o.x1_off=off_Wpc; o.x1_ks=128;
    o.y_off=off_Gc+512*1024; o.y_ks=1024; o.yt_off=off_G0+512; o.yt_rstride=1024; push(b,o); }
  push(b, SQ(off_cat,640,off_A0c,A0pc(0),A0pr(0)));
  push(b, SQ(off_catA1,1024,off_A1c,A1pc(0),A1pr(0)));
  { Op o=mko(); o.m_off=off_catA1+512; o.m_rstride=1024; o.x1_off=off_A0c;
    o.y_off=off_Gc+512; o.y_ks=1024; o.yt_off=off_G1; o.yt_rstride=1024; push(b,o); } // F10
  { Op o=mko(); o.m_off=off_cat+512; o.m_rstride=640; o.k1=128; o.x1_off=off_bpX; o.x1_ks=128;
    o.cols=64; o.bias_off=off_b0ah; o.scale=ALPHAF; o.y_off=off_Dc; o.y_ks=1024; push(b,o); } // c0
  push(b, P2op(1)); endg(b);
  // g1: F11, A0^4, A1^4, c1, P2 s2
  { Op o=mko(); o.m_off=off_catA1+512; o.m_rstride=1024; o.x1_off=off_Gc+512*1024; o.x1_ks=1024;
    o.add_off=off_A1c; o.y_off=off_Gc+512*1024+512; o.y_ks=1024;
    o.yt_off=off_G1+512; o.yt_rstride=1024; push(b,o); } // F11 = Wx1*E + A1
  push(b, SQ(A0pr(0),512,A0pc(0),A0pc(1),A0pr(1)));
  push(b, SQ(A1pr(0),512,A1pc(0),A1pc(1),A1pr(1)));
  { Op o=mko(); o.m_off=off_catA1+512; o.m_rstride=1024; o.x1_off=off_Dc; o.x1_ks=1024;
    o.cols=64; o.bias_off=off_b1ah; o.y_off=off_Dc+512; o.y_ks=1024; push(b,o); } // c1
  push(b, P2op(2)); endg(b);
  // g2..g4: power chains + P2 s3..s5
  for (int i=2;i<=4;++i){
    push(b, SQ(A0pr(i-1),512,A0pc(i-1),A0pc(i),A0pr(i)));
    push(b, SQ(A1pr(i-1),512,A1pc(i-1),A1pc(i),A1pr(i)));
    push(b, P2op(i+1)); endg(b);
  }
  // g5..g15: P2 s6..s16
  for (int s=6;s<=16;++s){ push(b, P2op(s)); endg(b); }
  // g16: Hillis-Steele level 0 (M = A0^16): Ga_j = g_j + M g_{j-1}
  { Op o=mko(); o.m_off=A0pr(3); o.cols=30*64; o.x1_off=off_Gb;
    o.add_off=off_Gb; o.add_s2=64; o.y_off=off_Ga; o.y_s2=64; push(b,o); }
  { Op o=mko(); o.k1=0; o.cols=64; o.add_off=off_Gb; o.y_off=off_Ga; push(b,o); }
  endg(b);
  // g17: level 1 (M = A0^32) -> sb_{j+1}
  { Op o=mko(); o.m_off=A0pr(4); o.cols=29*64; o.x1_off=off_Ga;
    o.add_off=off_Ga; o.add_s2=128; o.y_off=off_sb; o.y_s2=192; push(b,o); }
  { Op o=mko(); o.k1=0; o.cols=128; o.add_off=off_Ga; o.y_off=off_sb; o.y_s2=64; push(b,o); }
  endg(b);
  // g18..g35: phase C
  push(b, P4h(1)); endg(b);
  push(b, P4h(2)); endg(b);
  for (int s=3;s<=16;++s){ push(b, P4h(s)); push(b, P4rw(s)); endg(b); }
  push(b, P4rw(17)); endg(b);
  push(b, P4rw(18)); endg(b);
  // g36: fold1 + h0_final->S0 + GP2 = G^2
  push(b, FOLD(A1pr(3),1024,off_Rb,off_Fa,512,1.0f));
  { Op o=mko(); o.k1=0; o.cols=64; o.add_off=Hoff(16); o.add_s2=31*64; o.scale=ALPHAF;
    o.y_off=off_S; o.y_ks=1024; push(b,o); }
  push(b, SQG(off_G0, off_Gc, off_Gb, off_Ga)); endg(b);
  // g37: fold2 + GP4
  push(b, FOLD(A1pr(4),512,off_Fa,off_Fb,512,1.0f));
  push(b, SQG(off_Ga, off_Gb, off_Rb, off_Ra)); endg(b);
  // g38: h1_final (= fold2 block7, A1^64 terms negligible) -> S0 + GP8
  { Op o=mko(); o.k1=0; o.cols=64; o.add_off=off_Fb; o.add_s2=448; o.scale=ALPHAF;
    o.y_off=off_S+512; o.y_ks=1024; push(b,o); }
  push(b, SQG(off_Ra, off_Rb, off_H1, off_H0)); endg(b);
  // g39: GP16 + decode round 0
  push(b, SQG(off_H0, off_H1, -1, off_H2));
  push(b, DECA(0)); push(b, DECB(0)); endg(b);
  // g40..g42: decode rounds 1..3
  for (int k=1;k<=3;++k){ push(b, DECA(k)); push(b, DECB(k)); endg(b); }
  // g43: decode round 4
  push(b, DECA(4)); endg(b);
  // g44: output p_t = Wp h1_t * 256 + bp
  { Op o=mko(); o.m_off=off_Wpr; o.rows=128; o.cols=2048; o.x1_off=off_S+512; o.x1_ks=1024;
    o.bias_off=off_bph; o.scale=RALPHAF; o.out32=1; push(b,o); } endg(b);
  b.p.nops=b.nops; b.p.ng=b.ng;
  return b.p;
}
static constexpr Plan h_plan = build_plan();
__device__ __constant__ Plan d_plan = h_plan;

// ---------------- distributed grid barrier (32 arrival + 32 flag lines) ----
__device__ inline void grid_barrier(unsigned* ctrs, unsigned epoch) {
  __syncthreads();
  if (threadIdx.x == 0)
    __hip_atomic_fetch_add(&ctrs[(blockIdx.x & (NCTR-1))*32], 1u,
                           __ATOMIC_RELEASE, __HIP_MEMORY_SCOPE_AGENT);
  if (blockIdx.x == 0) {
    if (threadIdx.x < NCTR) {
      const unsigned tgt = epoch * (GRID / NCTR);
      while (__hip_atomic_load(&ctrs[threadIdx.x*32], __ATOMIC_ACQUIRE,
                               __HIP_MEMORY_SCOPE_AGENT) < tgt)
        __builtin_amdgcn_s_sleep(2);
    }
    __syncthreads();
    if (threadIdx.x < NCTR)
      __hip_atomic_store(&ctrs[(NCTR + threadIdx.x)*32], epoch,
                         __ATOMIC_RELEASE, __HIP_MEMORY_SCOPE_AGENT);
  } else if (threadIdx.x == 0) {
    const unsigned fl = (NCTR + (blockIdx.x & (NCTR-1)))*32;
    while (__hip_atomic_load(&ctrs[fl], __ATOMIC_ACQUIRE,
                             __HIP_MEMORY_SCOPE_AGENT) < epoch)
      __builtin_amdgcn_s_sleep(8);
  }
  __syncthreads();
}

// ---------------- GEMM tile machinery ----------------
__device__ inline void chunk_srcs(const Op& o, const f16* w, int r0, int c0, int kc,
                                  const f16*& pa, const f16*& pb) {
  const int tid = threadIdx.x;
  pa = w + o.m_off + (size_t)(r0 + (tid>>1)) * o.m_rstride + kc + (tid&1)*64;
  int C = c0 + (tid>>2);
  int xo, xks, xs1, xs2, xk;
  if (kc < o.k1) { xo=o.x1_off; xks=o.x1_ks; xs1=o.x1_s1; xs2=o.x1_s2; xk=kc; }
  else           { xo=o.x2_off; xks=o.x2_ks; xs1=o.x2_s1; xs2=o.x2_s2; xk=kc-o.k1; }
  int xcol = xs1*(C>>6) + (C&63) + xs2;
  pb = w + xo + (size_t)xcol*xks + xk + (tid&3)*32;
}

__device__ inline void ld_regs(const f16* pa, const f16* pb, f16x8 (&ra)[8], f16x8 (&rb)[4]) {
#pragma unroll
  for (int i=0;i<8;++i) ra[i] = *(const f16x8*)(pa + i*8);
#pragma unroll
  for (int i=0;i<4;++i) rb[i] = *(const f16x8*)(pb + i*8);
}

__device__ inline void st_lds(f16* lsA, f16* lsB, const f16x8 (&ra)[8], const f16x8 (&rb)[4]) {
  const int tid = threadIdx.x;
  f16* da = lsA + (tid>>1)*LDA + (tid&1)*64;
#pragma unroll
  for (int i=0;i<8;++i) *(f16x8*)(da + i*8) = ra[i];
  f16* db = lsB + (tid>>2)*LDA + (tid&3)*32;
#pragma unroll
  for (int i=0;i<4;++i) *(f16x8*)(db + i*8) = rb[i];
}

__device__ inline void zero_acc(f32x4 (&acc)[4][2]) {
#pragma unroll
  for (int s=0;s<4;++s)
#pragma unroll
    for (int c=0;c<2;++c) acc[s][c] = f32x4{0.f,0.f,0.f,0.f};
}

__device__ inline void mfma_lds(const f16* lsA, const f16* lsB, f32x4 (&acc)[4][2]) {
  const int tid = threadIdx.x, lane = tid & 63, wid = tid >> 6;
  const int wr = wid & 1, wc = wid >> 1;
  const int ko = (lane >> 4) * 8, rl = lane & 15;
#pragma unroll
  for (int kb = 0; kb < 4; ++kb) {
    f16x8 a[4], bb[2];
#pragma unroll
    for (int s = 0; s < 4; ++s)
      a[s] = *(const f16x8*)(lsA + (wr*64 + s*16 + rl) * LDA + kb*32 + ko);
#pragma unroll
    for (int c = 0; c < 2; ++c)
      bb[c] = *(const f16x8*)(lsB + (wc*32 + c*16 + rl) * LDA + kb*32 + ko);
#pragma unroll
    for (int s = 0; s < 4; ++s)
#pragma unroll
      for (int c = 0; c < 2; ++c)
        acc[s][c] = __builtin_amdgcn_mfma_f32_16x16x32_f16(a[s], bb[c], acc[s][c], 0, 0, 0);
  }
}

__device__ void run_tile(const Op& o, int local, f16* w, float* out, f16* lsA, f16* lsB) {
  int nct = o.cols >> 6;
  int rg = local / nct, ct = local - rg * nct;
  int r0 = rg << 7, c0 = ct << 6;
  f32x4 acc[4][2]; zero_acc(acc);
  int nch = (o.k1 + o.k2) >> 7;
  if (nch > 0) {
    const f16 *pa, *pb;
    f16x8 ra0[8], rb0[4], ra1[8], rb1[4];
    chunk_srcs(o, w, r0, c0, 0, pa, pb);
    ld_regs(pa, pb, ra0, rb0);
    if (nch > 1) { chunk_srcs(o, w, r0, c0, 128, pa, pb); ld_regs(pa, pb, ra1, rb1); }
    for (int c = 0; c < nch; ++c) {
      __syncthreads();
      if (c & 1) st_lds(lsA, lsB, ra1, rb1); else st_lds(lsA, lsB, ra0, rb0);
      __syncthreads();
      if (c + 2 < nch) {
        chunk_srcs(o, w, r0, c0, (c+2)*128, pa, pb);
        if (c & 1) ld_regs(pa, pb, ra1, rb1); else ld_regs(pa, pb, ra0, rb0);
      }
      mfma_lds(lsA, lsB, acc);
    }
  }
  const int tid = threadIdx.x, lane = tid & 63, wid = tid >> 6;
  const int wr = wid & 1, wc = wid >> 1, rb2 = (lane >> 4) * 4, cl = lane & 15;
#pragma unroll
  for (int s = 0; s < 4; ++s) {
    int r = r0 + wr*64 + s*16 + rb2;
#pragma unroll
    for (int c = 0; c < 2; ++c) {
      int C = c0 + wc*32 + c*16 + cl;
      f32x4 v = acc[s][c];
      if (o.add_off >= 0) {
        int acol = o.add_s1 * (C>>6) + (C&63) + o.add_s2;
        const f16* ap = w + o.add_off + (size_t)acol * o.add_ks + r;
        v[0]+=(float)ap[0]; v[1]+=(float)ap[1]; v[2]+=(float)ap[2]; v[3]+=(float)ap[3];
      }
      v[0]*=o.scale; v[1]*=o.scale; v[2]*=o.scale; v[3]*=o.scale;
      if (o.bias_off >= 0) {
        const f16* bb = w + o.bias_off + r;
        v[0]+=(float)bb[0]; v[1]+=(float)bb[1]; v[2]+=(float)bb[2]; v[3]+=(float)bb[3];
      }
      if (o.y_off >= 0) {
        int ycol = o.y_s1 * (C>>6) + (C&63) + o.y_s2;
        f16* yp = w + o.y_off + (size_t)ycol * o.y_ks + r;
        yp[0]=(f16)v[0]; yp[1]=(f16)v[1]; yp[2]=(f16)v[2]; yp[3]=(f16)v[3];
      }
      if (o.yt_off >= 0) {
        f16* tp = w + o.yt_off;
        tp[(size_t)(r+0)*o.yt_rstride + C] = (f16)v[0];
        tp[(size_t)(r+1)*o.yt_rstride + C] = (f16)v[1];
        tp[(size_t)(r+2)*o.yt_rstride + C] = (f16)v[2];
        tp[(size_t)(r+3)*o.yt_rstride + C] = (f16)v[3];
      }
      if (o.out32) {
        float* op2 = out + (size_t)(C & 63) * (NF*DIN) + (size_t)(C >> 6) * DIN + r;
        op2[0]=v[0]; op2[1]=v[1]; op2[2]=v[2]; op2[3]=v[3];
      }
    }
  }
}

__global__ __launch_bounds__(256, 1) void rnn_main(f16* w, float* out) {
  __shared__ f16 lsA[128*LDA];
  __shared__ f16 lsB[64*LDA];
  unsigned* ctrs = (unsigned*)(w + off_ctr);
  const int wg = blockIdx.x;
  const int ng = d_plan.ng;
  for (int g = 0; g < ng; ++g) {
    int o0 = d_plan.gstart[g], o1 = d_plan.gstart[g+1];
    int gtot = d_plan.gtiles[g];
    for (int t = wg; t < gtot; t += GRID) {
      int oi = o0;
      while (oi + 1 < o1 && t >= d_plan.ops[oi+1].tile_base) ++oi;
      run_tile(d_plan.ops[oi], t - d_plan.ops[oi].tile_base, w, out, lsA, lsB);
    }
    grid_barrier(ctrs, (unsigned)(g + 1));
  }
}

// ---------------- prep: convert/transpose weights, inputs, zeros ----------------
__global__ void rnn_prep(f16* w, const float* X, const float* Wx0, const float* b0,
    const float* Wh0, const float* d0p, const float* Wx1, const float* b1,
    const float* Wh1, const float* d1p, const float* Wp, const float* bp)
{
  const float d0 = d0p[0], d1 = d1p[0];
  const long n0=512L*640, n1=512L*1024, n2=(long)SZ, n3=(long)SZ, n4=128L*512, n5=512L*128,
             n6=(long)SZ, n6b=(long)SZ, n7=32768L*128, n8=512, n9=512, n10=512, n11=512,
             n12=128, n13=64L*128, n14=2048L*512, n15=2048L*512, n16=2048;
  const long total = n0+n1+n2+n3+n4+n5+n6+n6b+n7+n8+n9+n10+n11+n12+n13+n14+n15+n16;
  for (long idx = (long)blockIdx.x*blockDim.x + threadIdx.x; idx < total;
       idx += (long)gridDim.x*blockDim.x) {
    long j = idx;
    if (j < n0) { int r=(int)(j/640), c=(int)(j%640);
      w[off_cat+j] = (f16)(c<512 ? d0*Wh0[(long)r*512+c] : Wx0[(long)r*128+(c-512)]); continue; }
    j -= n0;
    if (j < n1) { int r=(int)(j>>10), c=(int)(j&1023);
      w[off_catA1+j] = (f16)(c<512 ? d1*Wh1[(long)r*512+c] : Wx1[(long)r*512+(c-512)]); continue; }
    j -= n1;
    if (j < n2) { int c=(int)(j>>9), r=(int)(j&511); w[off_A0c+j] = (f16)(d0*Wh0[(long)r*512+c]); continue; }
    j -= n2;
    if (j < n3) { int c=(int)(j>>9), r=(int)(j&511); w[off_A1c+j] = (f16)(d1*Wh1[(long)r*512+c]); continue; }
    j -= n3;
    if (j < n4) { w[off_Wpr+j] = (f16)Wp[j]; continue; }
    j -= n4;
    if (j < n5) { int c=(int)(j>>7), k=(int)(j&127); w[off_Wpc+j] = (f16)Wp[(long)k*512+c]; continue; }
    j -= n5;
    if (j < n6) { int r=(int)(j>>9), c=(int)(j&511);
      w[off_G0 + (long)r*1024 + c] = (f16)(d0*Wh0[(long)r*512+c]); continue; }
    j -= n6;
    if (j < n6b) { int c=(int)(j>>9), r=(int)(j&511);
      w[off_Gc + (long)c*1024 + r] = (f16)(d0*Wh0[(long)r*512+c]); continue; }
    j -= n6b;
    if (j < n7) { int col=(int)(j>>7), d=(int)(j&127); int t=col>>6, bb=col&63;
      w[off_Xin+j] = (f16)X[((long)bb<<16) + ((long)t<<7) + d]; continue; }
    j -= n7;
    if (j < n8) { w[off_b0h+j] = (f16)b0[j]; continue; }  j -= n8;
    if (j < n9) { w[off_b1h+j] = (f16)b1[j]; continue; }  j -= n9;
    if (j < n10){ w[off_b0ah+j] = (f16)(ALPHAF*b0[j]); continue; }  j -= n10;
    if (j < n11){ w[off_b1ah+j] = (f16)(ALPHAF*b1[j]); continue; }  j -= n11;
    if (j < n12){ w[off_bph+j] = (f16)bp[j]; continue; }  j -= n12;
    if (j < n13){ int k=(int)(j&127); w[off_bpX+j] = (f16)bp[k]; continue; }  j -= n13;
    if (j < n14){ w[off_Rb+j] = (f16)0.f; continue; }  j -= n14;
    if (j < n15){ w[off_sb+j] = (f16)0.f; continue; }  j -= n15;
    ((unsigned*)(w + off_ctr))[j] = 0u;
  }
}

extern "C" void kernel_launch(void* const* d_in, const int* in_sizes, int n_in,
                              void* d_out, int out_size, void* d_ws, size_t ws_size,
                              hipStream_t stream) {
  (void)in_sizes; (void)n_in; (void)out_size; (void)ws_size; // needs ~50 MB ws
  f16* w = (f16*)d_ws;
  hipLaunchKernelGGL(rnn_prep, dim3(2048), dim3(256), 0, stream,
      w,
      (const float*)d_in[0], (const float*)d_in[1], (const float*)d_in[2],
      (const float*)d_in[3], (const float*)d_in[4], (const float*)d_in[5],
      (const float*)d_in[6], (const float*)d_in[7], (const float*)d_in[8],
      (const float*)d_in[9], (const float*)d_in[10]);
  float* outp = (float*)d_out;
  void* kargs[] = { (void*)&w, (void*)&outp };
  hipLaunchCooperativeKernel((const void*)rnn_main, dim3(GRID), dim3(256), kargs, 0, stream);
}

// Round 7
// 1521.830 us; speedup vs baseline: 1.6660x; 1.6660x over previous
//
#include <hip/hip_runtime.h>
#include <cstddef>

// MultiStepLinearRNN: 2-layer linear RNN, T=512 encode + F=32 decode.
// R7: R2-PROVEN machinery (run_tile grid-GEMM, 52KB LDS, GRID 256, coop
// launch) with a restructured 29-group op table: 8-step chunks (64 chunks,
// 4096-col state), 3-level matrix Hillis-Steele scan, true-h P4 with lagged
// r-chain, 2-level fold + A1^32 special, affine-doubling decode with JIT
// G-power squarings. fp16 MFMA 16x16x32, fp32 accum.

typedef _Float16 f16;
typedef _Float16 f16x8 __attribute__((ext_vector_type(8)));
typedef float f32x4 __attribute__((ext_vector_type(4)));

#define GRID 256
#define NCTR 32
#define LDA  136     // LDS row stride in halves (128 + 8 pad)
#define ALPHAF 0.00390625f   // 2^-8 decode state pre-scale
#define RALPHAF 256.0f
#define DIN 128
#define NF 32

// ---------------- workspace layout (f16 element offsets) ----------------
constexpr int SZ = 512*512;
constexpr int off_cat   = 0;         // [512][640] = A0|Wx0 row-major
constexpr int off_catA1 = 327680;    // [512][1024] = A1|Wx1 row-major
constexpr int off_A0c   = 851968;    // A0 col-major [512c][512]
constexpr int off_A1c   = 1114112;
constexpr int off_Wpr   = 1376256;   // [128][512]
constexpr int off_Wpc   = 1441792;   // [512c][128]
constexpr int off_Gr    = 1507328;   // G row-major [1024][1024]
constexpr int off_Gc    = 2555904;   // G col-major
constexpr int off_P0    = 3604480;   // A0 powers: 3 (row,col) slot pairs
constexpr int off_P1    = 5177344;   // A1 powers: 3 slot pairs
constexpr int GPr       = 6750208;   // G-power slot P row
constexpr int GPc       = 7798784;   //            P col
constexpr int GQr       = 8847360;   //            Q row
constexpr int GQc       = 9895936;   //            Q col
constexpr int off_Xin   = 10944512;  // [32768c][128], col = t*64+b
constexpr int BA        = 15138816;  // 4 big buffers [4096c][512]
constexpr int BB        = 17235968;
constexpr int BC        = 19333120;
constexpr int BD        = 21430272;
constexpr int off_S     = 23527424;  // decode states [2048c][1024]
constexpr int off_Dc    = 25624576;  // b_1 [64c][1024]
constexpr int off_Db    = 25690112;  // b_2,4,8,16: 4 x [64c][1024]
constexpr int off_b0h   = 25952256;
constexpr int off_b1h   = 25952768;
constexpr int off_b0ah  = 25953280;
constexpr int off_b1ah  = 25953792;
constexpr int off_bph   = 25954304;
constexpr int off_bpX   = 25954432;  // bp replicated [64c][128]
constexpr int off_ctr   = 25962624;  // 2048 u32 barrier state
// end = 25966720 f16 = 49.5 MiB

constexpr int P0r(int s){ return off_P0 + s*524288; }
constexpr int P0c(int s){ return off_P0 + s*524288 + 262144; }
constexpr int P1r(int s){ return off_P1 + s*524288; }
constexpr int P1c(int s){ return off_P1 + s*524288 + 262144; }
constexpr int Bb(int k){ return k==0 ? off_Dc : off_Db + (k-1)*65536; }

// ---------------- op table ----------------
struct Op {
  int type;
  int m_off, m_rstride, rows, cols;
  int k1, x1_off, x1_ks, x1_s1, x1_s2;
  int k2, x2_off, x2_ks, x2_s1, x2_s2;
  int add_off, add_ks, add_s1, add_s2;
  int bias_off; float scale;
  int y_off, y_ks, y_s1, y_s2;
  int yt_off, yt_rstride;
  int out32, tile_base;
};
constexpr int MAXOPS = 80, MAXG = 32;
struct Plan { Op ops[MAXOPS]; int gstart[MAXG+1]; int gtiles[MAXG]; int nops, ng; };

constexpr Op mko() {
  Op o{};
  o.type=0; o.m_off=0; o.m_rstride=512; o.rows=512; o.cols=512;
  o.k1=512; o.x1_off=0; o.x1_ks=512; o.x1_s1=64; o.x1_s2=0;
  o.k2=0; o.x2_off=0; o.x2_ks=512; o.x2_s1=64; o.x2_s2=0;
  o.add_off=-1; o.add_ks=512; o.add_s1=64; o.add_s2=0;
  o.bias_off=-1; o.scale=1.0f;
  o.y_off=-1; o.y_ks=512; o.y_s1=64; o.y_s2=0;
  o.yt_off=-1; o.yt_rstride=512; o.out32=0; o.tile_base=0;
  return o;
}
constexpr int op_ntiles(const Op& o){ return (o.rows>>7)*(o.cols>>6); }

struct Builder { Plan p{}; int nops=0, ng=0, gtile=0; };
constexpr void push(Builder& b, Op o){ o.tile_base=b.gtile; b.gtile+=op_ntiles(o); b.p.ops[b.nops++]=o; }
constexpr void endg(Builder& b){ b.p.gtiles[b.ng]=b.gtile; b.ng++; b.p.gstart[b.ng]=b.nops; b.gtile=0; }

constexpr Op SQ2(int m,int mrs,int x1c,int yc,int yr){
  Op o=mko(); o.m_off=m; o.m_rstride=mrs; o.x1_off=x1c; o.y_off=yc; o.yt_off=yr; return o; }
constexpr Op SQG(int mr,int xc,int yc,int yr){
  Op o=mko(); o.rows=1024; o.cols=1024; o.k1=1024; o.m_off=mr; o.m_rstride=1024;
  o.x1_off=xc; o.x1_ks=1024; o.y_off=yc; o.y_ks=1024; o.yt_off=yr; o.yt_rstride=1024; return o; }
// P2 step s: chunk-local h superposition, g ends in BB (s=8)
constexpr Op P2S(int s){
  Op o=mko(); o.cols=4096; o.bias_off=off_b0h;
  o.k2=128; o.x2_off=off_Xin; o.x2_ks=128; o.x2_s1=512; o.x2_s2=(s-1)*64;
  o.y_off=(s&1)?BA:BB;
  if (s==1){ o.m_off=off_cat+512; o.m_rstride=640; o.k1=0; }
  else { o.m_off=off_cat; o.m_rstride=640; o.k1=512; o.x1_off=(s&1)?BB:BA; }
  return o; }
// P4 true-h step s (s=2..8): even s BB->BC, odd s BC->BB
constexpr Op HS(int s){
  Op o=mko(); o.m_off=off_cat; o.m_rstride=640; o.cols=4096;
  o.k1=512; o.x1_off=(s&1)?BC:BB;
  o.k2=128; o.x2_off=off_Xin; o.x2_ks=128; o.x2_s1=512; o.x2_s2=(s-1)*64;
  o.bias_off=off_b0h; o.y_off=(s&1)?BB:BC; return o; }
// r step s: r_s = A1 r_{s-1} + Wx1 h_s + b1 (r odd->BD, even->BA)
constexpr Op RS(int s){
  Op o=mko(); o.cols=4096; o.bias_off=off_b1h;
  if (s==1){ o.m_off=off_catA1+512; o.m_rstride=1024; o.k1=512; o.x1_off=BB; o.y_off=BD; }
  else { o.m_off=off_catA1; o.m_rstride=1024; o.k1=512; o.x1_off=(s&1)?BA:BD;
         o.k2=512; o.x2_off=(s&1)?BB:BC; o.x2_ks=512; o.x2_s1=64; o.x2_s2=0;
         o.y_off=(s&1)?BD:BA; }
  return o; }
// scan level: out[C+d*64] = M in[C] + in[C+d*64]
constexpr Op SCAN(int m,int d,int inb,int outb){
  Op o=mko(); o.m_off=m; o.cols=4096-d*64; o.x1_off=inb;
  o.add_off=inb; o.add_s2=d*64; o.y_off=outb; o.y_s2=d*64; return o; }
constexpr Op SCOPY(int d,int inb,int outb){
  Op o=mko(); o.k1=0; o.cols=d*64; o.add_off=inb; o.y_off=outb; return o; }
// pairwise fold: out[q] = M in[2q] + in[2q+1]
constexpr Op FOLDL(int m,int cols,int inb,int outb){
  Op o=mko(); o.m_off=m; o.cols=cols; o.x1_off=inb; o.x1_s1=128;
  o.add_off=inb; o.add_s1=128; o.add_s2=64; o.y_off=outb; return o; }
constexpr Op DECA(int k,int moff){
  Op o=mko(); int m=1<<k;
  o.rows=1024; o.cols=m*64; o.k1=1024; o.m_off=moff; o.m_rstride=1024;
  o.x1_off=off_S; o.x1_ks=1024; o.bias_off=Bb(k);
  o.y_off=off_S; o.y_ks=1024; o.y_s2=m*64; return o; }
constexpr Op DECB(int k,int moff){
  Op o=mko(); o.rows=1024; o.cols=64; o.k1=1024; o.m_off=moff; o.m_rstride=1024;
  o.x1_off=Bb(k); o.x1_ks=1024; o.bias_off=Bb(k);
  o.y_off=Bb(k+1); o.y_ks=1024; return o; }

constexpr Plan build_plan() {
  Builder b{}; b.p.gstart[0]=0;
  // g0: A0^2, A1^2, E, c0, P2 s1
  push(b, SQ2(off_cat,640,off_A0c,P0c(0),P0r(0)));
  push(b, SQ2(off_catA1,1024,off_A1c,P1c(0),P1r(0)));
  { Op o=mko(); o.m_off=off_cat+512; o.m_rstride=640; o.k1=128; o.x1_off=off_Wpc; o.x1_ks=128;
    o.y_off=off_Gc+512*1024; o.y_ks=1024; o.yt_off=off_Gr+512; o.yt_rstride=1024; push(b,o); } // E
  { Op o=mko(); o.m_off=off_cat+512; o.m_rstride=640; o.k1=128; o.x1_off=off_bpX; o.x1_ks=128;
    o.cols=64; o.bias_off=off_b0ah; o.scale=ALPHAF; o.y_off=off_Dc; o.y_ks=1024; push(b,o); } // c0
  push(b, P2S(1)); endg(b);
  // g1: A0^4, A1^4, F10, c1, P2 s2
  push(b, SQ2(P0r(0),512,P0c(0),P0c(1),P0r(1)));
  push(b, SQ2(P1r(0),512,P1c(0),P1c(1),P1r(1)));
  { Op o=mko(); o.m_off=off_catA1+512; o.m_rstride=1024; o.x1_off=off_A0c;
    o.y_off=off_Gc+512; o.y_ks=1024; o.yt_off=off_Gr+512*1024; o.yt_rstride=1024; push(b,o); } // F10
  { Op o=mko(); o.m_off=off_catA1+512; o.m_rstride=1024; o.x1_off=off_Dc; o.x1_ks=1024;
    o.cols=64; o.bias_off=off_b1ah; o.y_off=off_Dc+512; o.y_ks=1024; push(b,o); } // c1
  push(b, P2S(2)); endg(b);
  // g2: A0^8, A1^8, F11, P2 s3
  push(b, SQ2(P0r(1),512,P0c(1),P0c(2),P0r(2)));
  push(b, SQ2(P1r(1),512,P1c(1),P1c(2),P1r(2)));
  { Op o=mko(); o.m_off=off_catA1+512; o.m_rstride=1024; o.x1_off=off_Gc+512*1024; o.x1_ks=1024;
    o.add_off=off_A1c; o.y_off=off_Gc+512*1024+512; o.y_ks=1024;
    o.yt_off=off_Gr+512*1024+512; o.yt_rstride=1024; push(b,o); } // F11 = Wx1 E + A1
  push(b, P2S(3)); endg(b);
  // g3: A0^16, A1^16, P2 s4
  push(b, SQ2(P0r(2),512,P0c(2),P0c(0),P0r(0)));
  push(b, SQ2(P1r(2),512,P1c(2),P1c(0),P1r(0)));
  push(b, P2S(4)); endg(b);
  // g4: A0^32, A1^32, P2 s5
  push(b, SQ2(P0r(0),512,P0c(0),P0c(1),P0r(1)));
  push(b, SQ2(P1r(0),512,P1c(0),P1c(1),P1r(1)));
  push(b, P2S(5)); endg(b);
  // g5: P2 s6 + G^2
  push(b, P2S(6));
  push(b, SQG(off_Gr, off_Gc, GPc, GPr)); endg(b);
  // g6,g7: P2 s7, s8   (g = BB)
  push(b, P2S(7)); endg(b);
  push(b, P2S(8)); endg(b);
  // g8..g10: scan levels (A0^8, A0^16, A0^32) -> final in BA
  push(b, SCAN(P0r(2), 1, BB, BA)); push(b, SCOPY(1, BB, BA)); endg(b);
  push(b, SCAN(P0r(0), 2, BA, BB)); push(b, SCOPY(2, BA, BB)); endg(b);
  push(b, SCAN(P0r(1), 4, BB, BA)); push(b, SCOPY(4, BB, BA)); endg(b);
  // g11: h1 (shifted chunk-start read) -> BB
  { Op o=mko(); o.m_off=off_cat; o.m_rstride=640; o.cols=4032; o.k1=512; o.x1_off=BA;
    o.k2=128; o.x2_off=off_Xin; o.x2_ks=128; o.x2_s1=512; o.x2_s2=512;
    o.bias_off=off_b0h; o.y_off=BB; o.y_s2=64; push(b,o); }
  { Op o=mko(); o.m_off=off_cat+512; o.m_rstride=640; o.cols=64; o.k1=0;
    o.k2=128; o.x2_off=off_Xin; o.x2_ks=128; o.x2_s1=512; o.x2_s2=0;
    o.bias_off=off_b0h; o.y_off=BB; push(b,o); }
  endg(b);
  // g12..g18: {h(s+1), r(s)} for s=1..7
  for (int s=1; s<=7; ++s){ push(b, HS(s+1)); push(b, RS(s)); endg(b); }
  // g19: r8 + h0_final -> S top
  push(b, RS(8));
  { Op o=mko(); o.k1=0; o.cols=64; o.add_off=BC; o.add_s2=4032; o.scale=ALPHAF;
    o.y_off=off_S; o.y_ks=1024; push(b,o); }
  endg(b);
  // g20,g21: fold l0 (A1^8), l1 (A1^16)
  push(b, FOLDL(P1r(2), 2048, BA, BB)); endg(b);
  push(b, FOLDL(P1r(0), 1024, BB, BC)); endg(b);
  // g22: h1_final = v15 + A1^32 v14 -> S bottom
  { Op o=mko(); o.m_off=P1r(1); o.cols=64; o.x1_off=BC; o.x1_s2=896;
    o.add_off=BC; o.add_s2=960; o.scale=ALPHAF;
    o.y_off=off_S+512; o.y_ks=1024; push(b,o); }
  endg(b);
  // g23..g27: decode doubling with JIT G squarings
  push(b, DECA(0, off_Gr)); push(b, DECB(0, off_Gr)); endg(b);
  push(b, DECA(1, GPr)); push(b, DECB(1, GPr)); push(b, SQG(GPr,GPc,GQc,GQr)); endg(b);
  push(b, DECA(2, GQr)); push(b, DECB(2, GQr)); push(b, SQG(GQr,GQc,GPc,GPr)); endg(b);
  push(b, DECA(3, GPr)); push(b, DECB(3, GPr)); push(b, SQG(GPr,GPc,GQc,GQr)); endg(b);
  push(b, DECA(4, GQr)); endg(b);
  // g28: output p_t = 256 * (Wp h1_t) + bp
  { Op o=mko(); o.m_off=off_Wpr; o.rows=128; o.cols=2048; o.x1_off=off_S+512; o.x1_ks=1024;
    o.bias_off=off_bph; o.scale=RALPHAF; o.out32=1; push(b,o); }
  endg(b);
  b.p.nops=b.nops; b.p.ng=b.ng;
  return b.p;
}
static constexpr Plan h_plan = build_plan();
__device__ __constant__ Plan d_plan = h_plan;

// ---------------- grid barrier (R2-proven) ----------------
__device__ inline void grid_barrier(unsigned* ctrs, unsigned* flag, unsigned epoch) {
  __syncthreads();
  if (threadIdx.x == 0)
    __hip_atomic_fetch_add(&ctrs[(blockIdx.x & (NCTR-1))*32], 1u,
                           __ATOMIC_RELEASE, __HIP_MEMORY_SCOPE_AGENT);
  if (blockIdx.x == 0) {
    if (threadIdx.x < NCTR) {
      const unsigned tgt = epoch * (GRID / NCTR);
      while (__hip_atomic_load(&ctrs[threadIdx.x*32], __ATOMIC_ACQUIRE,
                               __HIP_MEMORY_SCOPE_AGENT) < tgt)
        __builtin_amdgcn_s_sleep(2);
    }
    __syncthreads();
    if (threadIdx.x == 0)
      __hip_atomic_store(flag, epoch, __ATOMIC_RELEASE, __HIP_MEMORY_SCOPE_AGENT);
  } else if (threadIdx.x == 0) {
    while (__hip_atomic_load(flag, __ATOMIC_ACQUIRE, __HIP_MEMORY_SCOPE_AGENT) < epoch)
      __builtin_amdgcn_s_sleep(2);
  }
  __syncthreads();
}

// ---------------- GEMM tile machinery (R2-proven) ----------------
__device__ inline void chunk_srcs(const Op& o, const f16* w, int r0, int c0, int kc,
                                  const f16*& pa, const f16*& pb) {
  const int tid = threadIdx.x;
  pa = w + o.m_off + (size_t)(r0 + (tid>>1)) * o.m_rstride + kc + (tid&1)*64;
  int C = c0 + (tid>>2);
  int xo, xks, xs1, xs2, xk;
  if (kc < o.k1) { xo=o.x1_off; xks=o.x1_ks; xs1=o.x1_s1; xs2=o.x1_s2; xk=kc; }
  else           { xo=o.x2_off; xks=o.x2_ks; xs1=o.x2_s1; xs2=o.x2_s2; xk=kc-o.k1; }
  int xcol = xs1*(C>>6) + (C&63) + xs2;
  pb = w + xo + (size_t)xcol*xks + xk + (tid&3)*32;
}

__device__ inline void ld_regs(const f16* pa, const f16* pb, f16x8 (&ra)[8], f16x8 (&rb)[4]) {
#pragma unroll
  for (int i=0;i<8;++i) ra[i] = *(const f16x8*)(pa + i*8);
#pragma unroll
  for (int i=0;i<4;++i) rb[i] = *(const f16x8*)(pb + i*8);
}

__device__ inline void st_lds(f16* lsA, f16* lsB, const f16x8 (&ra)[8], const f16x8 (&rb)[4]) {
  const int tid = threadIdx.x;
  f16* da = lsA + (tid>>1)*LDA + (tid&1)*64;
#pragma unroll
  for (int i=0;i<8;++i) *(f16x8*)(da + i*8) = ra[i];
  f16* db = lsB + (tid>>2)*LDA + (tid&3)*32;
#pragma unroll
  for (int i=0;i<4;++i) *(f16x8*)(db + i*8) = rb[i];
}

__device__ inline void mfma_lds(const f16* lsA, const f16* lsB, f32x4 (&acc)[4][2]) {
  const int tid = threadIdx.x, lane = tid & 63, wid = tid >> 6;
  const int wr = wid & 1, wc = wid >> 1;
  const int ko = (lane >> 4) * 8, rl = lane & 15;
#pragma unroll
  for (int kb = 0; kb < 4; ++kb) {
    f16x8 a[4], bb[2];
#pragma unroll
    for (int s = 0; s < 4; ++s)
      a[s] = *(const f16x8*)(lsA + (wr*64 + s*16 + rl) * LDA + kb*32 + ko);
#pragma unroll
    for (int c = 0; c < 2; ++c)
      bb[c] = *(const f16x8*)(lsB + (wc*32 + c*16 + rl) * LDA + kb*32 + ko);
#pragma unroll
    for (int s = 0; s < 4; ++s)
#pragma unroll
      for (int c = 0; c < 2; ++c)
        acc[s][c] = __builtin_amdgcn_mfma_f32_16x16x32_f16(a[s], bb[c], acc[s][c], 0, 0, 0);
  }
}

__device__ void run_tile(const Op& o, int local, f16* w, float* out, f16* lsA, f16* lsB) {
  int nct = o.cols >> 6;
  int rg = local / nct, ct = local - rg * nct;
  int r0 = rg << 7, c0 = ct << 6;
  f32x4 acc[4][2];
#pragma unroll
  for (int s=0;s<4;++s)
#pragma unroll
    for (int c=0;c<2;++c) acc[s][c] = f32x4{0.f,0.f,0.f,0.f};
  int nch = (o.k1 + o.k2) >> 7;
  if (nch > 0) {
    const f16 *pa, *pb;
    f16x8 ra[8], rb[4];
    chunk_srcs(o, w, r0, c0, 0, pa, pb);
    ld_regs(pa, pb, ra, rb);
    for (int c = 0; c < nch; ++c) {
      __syncthreads();
      st_lds(lsA, lsB, ra, rb);
      __syncthreads();
      if (c + 1 < nch) { chunk_srcs(o, w, r0, c0, (c+1)*128, pa, pb); ld_regs(pa, pb, ra, rb); }
      mfma_lds(lsA, lsB, acc);
    }
  }
  const int tid = threadIdx.x, lane = tid & 63, wid = tid >> 6;
  const int wr = wid & 1, wc = wid >> 1, rb2 = (lane >> 4) * 4, cl = lane & 15;
#pragma unroll
  for (int s = 0; s < 4; ++s) {
    int r = r0 + wr*64 + s*16 + rb2;
#pragma unroll
    for (int c = 0; c < 2; ++c) {
      int C = c0 + wc*32 + c*16 + cl;
      f32x4 v = acc[s][c];
      if (o.add_off >= 0) {
        int acol = o.add_s1 * (C>>6) + (C&63) + o.add_s2;
        const f16* ap = w + o.add_off + (size_t)acol * o.add_ks + r;
        v[0]+=(float)ap[0]; v[1]+=(float)ap[1]; v[2]+=(float)ap[2]; v[3]+=(float)ap[3];
      }
      v[0]*=o.scale; v[1]*=o.scale; v[2]*=o.scale; v[3]*=o.scale;
      if (o.bias_off >= 0) {
        const f16* bb = w + o.bias_off + r;
        v[0]+=(float)bb[0]; v[1]+=(float)bb[1]; v[2]+=(float)bb[2]; v[3]+=(float)bb[3];
      }
      if (o.y_off >= 0) {
        int ycol = o.y_s1 * (C>>6) + (C&63) + o.y_s2;
        f16* yp = w + o.y_off + (size_t)ycol * o.y_ks + r;
        yp[0]=(f16)v[0]; yp[1]=(f16)v[1]; yp[2]=(f16)v[2]; yp[3]=(f16)v[3];
      }
      if (o.yt_off >= 0) {
        f16* tp = w + o.yt_off;
        tp[(size_t)(r+0)*o.yt_rstride + C] = (f16)v[0];
        tp[(size_t)(r+1)*o.yt_rstride + C] = (f16)v[1];
        tp[(size_t)(r+2)*o.yt_rstride + C] = (f16)v[2];
        tp[(size_t)(r+3)*o.yt_rstride + C] = (f16)v[3];
      }
      if (o.out32) {
        float* op2 = out + (size_t)(C & 63) * (NF*DIN) + (size_t)(C >> 6) * DIN + r;
        op2[0]=v[0]; op2[1]=v[1]; op2[2]=v[2]; op2[3]=v[3];
      }
    }
  }
}

__global__ __launch_bounds__(256, 1) void rnn_main(f16* w, float* out) {
  __shared__ f16 lsA[128*LDA];
  __shared__ f16 lsB[64*LDA];
  unsigned* ctrs = (unsigned*)(w + off_ctr);
  unsigned* flag = ctrs + NCTR*32;
  const int wg = blockIdx.x;
  const int ng = d_plan.ng;
  for (int g = 0; g < ng; ++g) {
    int o0 = d_plan.gstart[g], o1 = d_plan.gstart[g+1];
    int gtot = d_plan.gtiles[g];
    for (int t = wg; t < gtot; t += GRID) {
      int oi = o0;
      while (oi + 1 < o1 && t >= d_plan.ops[oi+1].tile_base) ++oi;
      run_tile(d_plan.ops[oi], t - d_plan.ops[oi].tile_base, w, out, lsA, lsB);
    }
    grid_barrier(ctrs, flag, (unsigned)(g + 1));
  }
}

// ---------------- prep ----------------
__global__ void rnn_prep(f16* w, const float* X, const float* Wx0, const float* b0,
    const float* Wh0, const float* d0p, const float* Wx1, const float* b1,
    const float* Wh1, const float* d1p, const float* Wp, const float* bp)
{
  const float d0 = d0p[0], d1 = d1p[0];
  const long n0=512L*640, n1=512L*1024, n2=(long)SZ, n3=(long)SZ, n4=128L*512, n5=512L*128,
             n6=(long)SZ, n7=(long)SZ, n8=32768L*128, n9=512, n10=512, n11=512, n12=512,
             n13=128, n14=64L*128, n15=2048;
  const long total = n0+n1+n2+n3+n4+n5+n6+n7+n8+n9+n10+n11+n12+n13+n14+n15;
  for (long idx = (long)blockIdx.x*blockDim.x + threadIdx.x; idx < total;
       idx += (long)gridDim.x*blockDim.x) {
    long j = idx;
    if (j < n0) { int r=(int)(j/640), c=(int)(j%640);
      w[off_cat+j] = (f16)(c<512 ? d0*Wh0[(long)r*512+c] : Wx0[(long)r*128+(c-512)]); continue; }
    j -= n0;
    if (j < n1) { int r=(int)(j>>10), c=(int)(j&1023);
      w[off_catA1+j] = (f16)(c<512 ? d1*Wh1[(long)r*512+c] : Wx1[(long)r*512+(c-512)]); continue; }
    j -= n1;
    if (j < n2) { int c=(int)(j>>9), r=(int)(j&511); w[off_A0c+j] = (f16)(d0*Wh0[(long)r*512+c]); continue; }
    j -= n2;
    if (j < n3) { int c=(int)(j>>9), r=(int)(j&511); w[off_A1c+j] = (f16)(d1*Wh1[(long)r*512+c]); continue; }
    j -= n3;
    if (j < n4) { w[off_Wpr+j] = (f16)Wp[j]; continue; }
    j -= n4;
    if (j < n5) { int c=(int)(j>>7), k=(int)(j&127); w[off_Wpc+j] = (f16)Wp[(long)k*512+c]; continue; }
    j -= n5;
    if (j < n6) { int r=(int)(j>>9), c=(int)(j&511);
      w[off_Gr + (long)r*1024 + c] = (f16)(d0*Wh0[(long)r*512+c]); continue; }
    j -= n6;
    if (j < n7) { int c=(int)(j>>9), r=(int)(j&511);
      w[off_Gc + (long)c*1024 + r] = (f16)(d0*Wh0[(long)r*512+c]); continue; }
    j -= n7;
    if (j < n8) { int col=(int)(j>>7), d=(int)(j&127); int t=col>>6, bb=col&63;
      w[off_Xin+j] = (f16)X[((long)bb<<16) + ((long)t<<7) + d]; continue; }
    j -= n8;
    if (j < n9) { w[off_b0h+j] = (f16)b0[j]; continue; }  j -= n9;
    if (j < n10){ w[off_b1h+j] = (f16)b1[j]; continue; }  j -= n10;
    if (j < n11){ w[off_b0ah+j] = (f16)(ALPHAF*b0[j]); continue; }  j -= n11;
    if (j < n12){ w[off_b1ah+j] = (f16)(ALPHAF*b1[j]); continue; }  j -= n12;
    if (j < n13){ w[off_bph+j] = (f16)bp[j]; continue; }  j -= n13;
    if (j < n14){ int k=(int)(j&127); w[off_bpX+j] = (f16)bp[k]; continue; }  j -= n14;
    ((unsigned*)(w + off_ctr))[j] = 0u;
  }
}

extern "C" void kernel_launch(void* const* d_in, const int* in_sizes, int n_in,
                              void* d_out, int out_size, void* d_ws, size_t ws_size,
                              hipStream_t stream) {
  (void)in_sizes; (void)n_in; (void)out_size; (void)ws_size; // needs ~50 MB ws
  f16* w = (f16*)d_ws;
  hipLaunchKernelGGL(rnn_prep, dim3(2048), dim3(256), 0, stream,
      w,
      (const float*)d_in[0], (const float*)d_in[1], (const float*)d_in[2],
      (const float*)d_in[3], (const float*)d_in[4], (const float*)d_in[5],
      (const float*)d_in[6], (const float*)d_in[7], (const float*)d_in[8],
      (const float*)d_in[9], (const float*)d_in[10]);
  float* outp = (float*)d_out;
  void* kargs[] = { (void*)&w, (void*)&outp };
  hipLaunchCooperativeKernel((const void*)rnn_main, dim3(GRID), dim3(256), kargs, 0, stream);
}

// Round 8
// 849.440 us; speedup vs baseline: 2.9847x; 1.7916x over previous
//
#include <hip/hip_runtime.h>
#include <cstddef>

// MultiStepLinearRNN: 2-layer linear RNN, T=512 encode + F=32 decode.
// R8 = R7 plan (29 groups, PROVEN at 1521us) with ONE mechanism change:
// inter-group state data moves through the device-coherent LLC via sc0/sc1
// (L1+L2-bypass) loads/stores; static weights keep plain cached loads (L2
// stays warm -- no more fence-driven invalidation); grid barrier uses
// RELAXED atomics + sc0sc1 polls, zero cache-maintenance fences.
// fp16 MFMA 16x16x32, fp32 accum.

typedef _Float16 f16;
typedef _Float16 f16x8 __attribute__((ext_vector_type(8)));
typedef _Float16 f16x4 __attribute__((ext_vector_type(4)));
typedef float f32x4 __attribute__((ext_vector_type(4)));

#define GRID 256
#define NCTR 32
#define LDA  136     // LDS row stride in halves (128 + 8 pad)
#define ALPHAF 0.00390625f   // 2^-8 decode state pre-scale
#define RALPHAF 256.0f
#define DIN 128
#define NF 32

// ---------------- workspace layout (f16 element offsets) ----------------
constexpr int SZ = 512*512;
constexpr int off_cat   = 0;         // [512][640] = A0|Wx0 row-major   [static]
constexpr int off_catA1 = 327680;    // [512][1024] = A1|Wx1 row-major  [static]
constexpr int off_A0c   = 851968;    // A0 col-major [512c][512]        [static]
constexpr int off_A1c   = 1114112;   //                                 [static]
constexpr int off_Wpr   = 1376256;   // [128][512]                      [static]
constexpr int off_Wpc   = 1441792;   // [512c][128]                     [static]
constexpr int off_Gr    = 1507328;   // G row-major [1024][1024]        [dynamic from here]
constexpr int off_Gc    = 2555904;   // G col-major
constexpr int off_P0    = 3604480;   // A0 powers: 3 (row,col) slot pairs
constexpr int off_P1    = 5177344;   // A1 powers: 3 slot pairs
constexpr int GPr       = 6750208;   // G-power slot P row
constexpr int GPc       = 7798784;
constexpr int GQr       = 8847360;
constexpr int GQc       = 9895936;
constexpr int off_Xin   = 10944512;  // [32768c][128], col = t*64+b     [static]
constexpr int BA        = 15138816;  // 4 big buffers [4096c][512]      [dynamic]
constexpr int BB        = 17235968;
constexpr int BC        = 19333120;
constexpr int BD        = 21430272;
constexpr int off_S     = 23527424;  // decode states [2048c][1024]
constexpr int off_Dc    = 25624576;  // b_1 [64c][1024]
constexpr int off_Db    = 25690112;  // b_2,4,8,16: 4 x [64c][1024]
constexpr int off_b0h   = 25952256;  // [static from here]
constexpr int off_b1h   = 25952768;
constexpr int off_b0ah  = 25953280;
constexpr int off_b1ah  = 25953792;
constexpr int off_bph   = 25954304;
constexpr int off_bpX   = 25954432;  // bp replicated [64c][128]
constexpr int off_ctr   = 25962624;  // 2048 u32 barrier state
// end = 25966720 f16 = 49.5 MiB

// dynamic (kernel-rewritten) address classifier: these MUST use sc0sc1 ops
__host__ __device__ constexpr bool dynb(int off){
  return (off >= off_Gr && off < off_Xin) || (off >= BA && off < off_b0h);
}

constexpr int P0r(int s){ return off_P0 + s*524288; }
constexpr int P0c(int s){ return off_P0 + s*524288 + 262144; }
constexpr int P1r(int s){ return off_P1 + s*524288; }
constexpr int P1c(int s){ return off_P1 + s*524288 + 262144; }
constexpr int Bb(int k){ return k==0 ? off_Dc : off_Db + (k-1)*65536; }

// ---------------- op table ----------------
struct Op {
  int type;
  int m_off, m_rstride, rows, cols;
  int k1, x1_off, x1_ks, x1_s1, x1_s2;
  int k2, x2_off, x2_ks, x2_s1, x2_s2;
  int add_off, add_ks, add_s1, add_s2;
  int bias_off; float scale;
  int y_off, y_ks, y_s1, y_s2;
  int yt_off, yt_rstride;
  int out32, tile_base;
};
constexpr int MAXOPS = 80, MAXG = 32;
struct Plan { Op ops[MAXOPS]; int gstart[MAXG+1]; int gtiles[MAXG]; int nops, ng; };

constexpr Op mko() {
  Op o{};
  o.type=0; o.m_off=0; o.m_rstride=512; o.rows=512; o.cols=512;
  o.k1=512; o.x1_off=0; o.x1_ks=512; o.x1_s1=64; o.x1_s2=0;
  o.k2=0; o.x2_off=0; o.x2_ks=512; o.x2_s1=64; o.x2_s2=0;
  o.add_off=-1; o.add_ks=512; o.add_s1=64; o.add_s2=0;
  o.bias_off=-1; o.scale=1.0f;
  o.y_off=-1; o.y_ks=512; o.y_s1=64; o.y_s2=0;
  o.yt_off=-1; o.yt_rstride=512; o.out32=0; o.tile_base=0;
  return o;
}
constexpr int op_ntiles(const Op& o){ return (o.rows>>7)*(o.cols>>6); }

struct Builder { Plan p{}; int nops=0, ng=0, gtile=0; };
constexpr void push(Builder& b, Op o){ o.tile_base=b.gtile; b.gtile+=op_ntiles(o); b.p.ops[b.nops++]=o; }
constexpr void endg(Builder& b){ b.p.gtiles[b.ng]=b.gtile; b.ng++; b.p.gstart[b.ng]=b.nops; b.gtile=0; }

constexpr Op SQ2(int m,int mrs,int x1c,int yc,int yr){
  Op o=mko(); o.m_off=m; o.m_rstride=mrs; o.x1_off=x1c; o.y_off=yc; o.yt_off=yr; return o; }
constexpr Op SQG(int mr,int xc,int yc,int yr){
  Op o=mko(); o.rows=1024; o.cols=1024; o.k1=1024; o.m_off=mr; o.m_rstride=1024;
  o.x1_off=xc; o.x1_ks=1024; o.y_off=yc; o.y_ks=1024; o.yt_off=yr; o.yt_rstride=1024; return o; }
constexpr Op P2S(int s){
  Op o=mko(); o.cols=4096; o.bias_off=off_b0h;
  o.k2=128; o.x2_off=off_Xin; o.x2_ks=128; o.x2_s1=512; o.x2_s2=(s-1)*64;
  o.y_off=(s&1)?BA:BB;
  if (s==1){ o.m_off=off_cat+512; o.m_rstride=640; o.k1=0; }
  else { o.m_off=off_cat; o.m_rstride=640; o.k1=512; o.x1_off=(s&1)?BB:BA; }
  return o; }
constexpr Op HS(int s){
  Op o=mko(); o.m_off=off_cat; o.m_rstride=640; o.cols=4096;
  o.k1=512; o.x1_off=(s&1)?BC:BB;
  o.k2=128; o.x2_off=off_Xin; o.x2_ks=128; o.x2_s1=512; o.x2_s2=(s-1)*64;
  o.bias_off=off_b0h; o.y_off=(s&1)?BB:BC; return o; }
constexpr Op RS(int s){
  Op o=mko(); o.cols=4096; o.bias_off=off_b1h;
  if (s==1){ o.m_off=off_catA1+512; o.m_rstride=1024; o.k1=512; o.x1_off=BB; o.y_off=BD; }
  else { o.m_off=off_catA1; o.m_rstride=1024; o.k1=512; o.x1_off=(s&1)?BA:BD;
         o.k2=512; o.x2_off=(s&1)?BB:BC; o.x2_ks=512; o.x2_s1=64; o.x2_s2=0;
         o.y_off=(s&1)?BD:BA; }
  return o; }
constexpr Op SCAN(int m,int d,int inb,int outb){
  Op o=mko(); o.m_off=m; o.cols=4096-d*64; o.x1_off=inb;
  o.add_off=inb; o.add_s2=d*64; o.y_off=outb; o.y_s2=d*64; return o; }
constexpr Op SCOPY(int d,int inb,int outb){
  Op o=mko(); o.k1=0; o.cols=d*64; o.add_off=inb; o.y_off=outb; return o; }
constexpr Op FOLDL(int m,int cols,int inb,int outb){
  Op o=mko(); o.m_off=m; o.cols=cols; o.x1_off=inb; o.x1_s1=128;
  o.add_off=inb; o.add_s1=128; o.add_s2=64; o.y_off=outb; return o; }
constexpr Op DECA(int k,int moff){
  Op o=mko(); int m=1<<k;
  o.rows=1024; o.cols=m*64; o.k1=1024; o.m_off=moff; o.m_rstride=1024;
  o.x1_off=off_S; o.x1_ks=1024; o.bias_off=Bb(k);
  o.y_off=off_S; o.y_ks=1024; o.y_s2=m*64; return o; }
constexpr Op DECB(int k,int moff){
  Op o=mko(); o.rows=1024; o.cols=64; o.k1=1024; o.m_off=moff; o.m_rstride=1024;
  o.x1_off=Bb(k); o.x1_ks=1024; o.bias_off=Bb(k);
  o.y_off=Bb(k+1); o.y_ks=1024; return o; }

constexpr Plan build_plan() {
  Builder b{}; b.p.gstart[0]=0;
  // g0: A0^2, A1^2, E, c0, P2 s1
  push(b, SQ2(off_cat,640,off_A0c,P0c(0),P0r(0)));
  push(b, SQ2(off_catA1,1024,off_A1c,P1c(0),P1r(0)));
  { Op o=mko(); o.m_off=off_cat+512; o.m_rstride=640; o.k1=128; o.x1_off=off_Wpc; o.x1_ks=128;
    o.y_off=off_Gc+512*1024; o.y_ks=1024; o.yt_off=off_Gr+512; o.yt_rstride=1024; push(b,o); } // E
  { Op o=mko(); o.m_off=off_cat+512; o.m_rstride=640; o.k1=128; o.x1_off=off_bpX; o.x1_ks=128;
    o.cols=64; o.bias_off=off_b0ah; o.scale=ALPHAF; o.y_off=off_Dc; o.y_ks=1024; push(b,o); } // c0
  push(b, P2S(1)); endg(b);
  // g1: A0^4, A1^4, F10, c1, P2 s2
  push(b, SQ2(P0r(0),512,P0c(0),P0c(1),P0r(1)));
  push(b, SQ2(P1r(0),512,P1c(0),P1c(1),P1r(1)));
  { Op o=mko(); o.m_off=off_catA1+512; o.m_rstride=1024; o.x1_off=off_A0c;
    o.y_off=off_Gc+512; o.y_ks=1024; o.yt_off=off_Gr+512*1024; o.yt_rstride=1024; push(b,o); } // F10
  { Op o=mko(); o.m_off=off_catA1+512; o.m_rstride=1024; o.x1_off=off_Dc; o.x1_ks=1024;
    o.cols=64; o.bias_off=off_b1ah; o.y_off=off_Dc+512; o.y_ks=1024; push(b,o); } // c1
  push(b, P2S(2)); endg(b);
  // g2: A0^8, A1^8, F11, P2 s3
  push(b, SQ2(P0r(1),512,P0c(1),P0c(2),P0r(2)));
  push(b, SQ2(P1r(1),512,P1c(1),P1c(2),P1r(2)));
  { Op o=mko(); o.m_off=off_catA1+512; o.m_rstride=1024; o.x1_off=off_Gc+512*1024; o.x1_ks=1024;
    o.add_off=off_A1c; o.y_off=off_Gc+512*1024+512; o.y_ks=1024;
    o.yt_off=off_Gr+512*1024+512; o.yt_rstride=1024; push(b,o); } // F11 = Wx1 E + A1
  push(b, P2S(3)); endg(b);
  // g3: A0^16, A1^16, P2 s4
  push(b, SQ2(P0r(2),512,P0c(2),P0c(0),P0r(0)));
  push(b, SQ2(P1r(2),512,P1c(2),P1c(0),P1r(0)));
  push(b, P2S(4)); endg(b);
  // g4: A0^32, A1^32, P2 s5
  push(b, SQ2(P0r(0),512,P0c(0),P0c(1),P0r(1)));
  push(b, SQ2(P1r(0),512,P1c(0),P1c(1),P1r(1)));
  push(b, P2S(5)); endg(b);
  // g5: P2 s6 + G^2
  push(b, P2S(6));
  push(b, SQG(off_Gr, off_Gc, GPc, GPr)); endg(b);
  // g6,g7: P2 s7, s8   (g = BB)
  push(b, P2S(7)); endg(b);
  push(b, P2S(8)); endg(b);
  // g8..g10: scan levels (A0^8, A0^16, A0^32) -> final in BA
  push(b, SCAN(P0r(2), 1, BB, BA)); push(b, SCOPY(1, BB, BA)); endg(b);
  push(b, SCAN(P0r(0), 2, BA, BB)); push(b, SCOPY(2, BA, BB)); endg(b);
  push(b, SCAN(P0r(1), 4, BB, BA)); push(b, SCOPY(4, BB, BA)); endg(b);
  // g11: h1 (shifted chunk-start read) -> BB
  { Op o=mko(); o.m_off=off_cat; o.m_rstride=640; o.cols=4032; o.k1=512; o.x1_off=BA;
    o.k2=128; o.x2_off=off_Xin; o.x2_ks=128; o.x2_s1=512; o.x2_s2=512;
    o.bias_off=off_b0h; o.y_off=BB; o.y_s2=64; push(b,o); }
  { Op o=mko(); o.m_off=off_cat+512; o.m_rstride=640; o.cols=64; o.k1=0;
    o.k2=128; o.x2_off=off_Xin; o.x2_ks=128; o.x2_s1=512; o.x2_s2=0;
    o.bias_off=off_b0h; o.y_off=BB; push(b,o); }
  endg(b);
  // g12..g18: {h(s+1), r(s)} for s=1..7
  for (int s=1; s<=7; ++s){ push(b, HS(s+1)); push(b, RS(s)); endg(b); }
  // g19: r8 + h0_final -> S top
  push(b, RS(8));
  { Op o=mko(); o.k1=0; o.cols=64; o.add_off=BC; o.add_s2=4032; o.scale=ALPHAF;
    o.y_off=off_S; o.y_ks=1024; push(b,o); }
  endg(b);
  // g20,g21: fold l0 (A1^8), l1 (A1^16)
  push(b, FOLDL(P1r(2), 2048, BA, BB)); endg(b);
  push(b, FOLDL(P1r(0), 1024, BB, BC)); endg(b);
  // g22: h1_final = v15 + A1^32 v14 -> S bottom
  { Op o=mko(); o.m_off=P1r(1); o.cols=64; o.x1_off=BC; o.x1_s2=896;
    o.add_off=BC; o.add_s2=960; o.scale=ALPHAF;
    o.y_off=off_S+512; o.y_ks=1024; push(b,o); }
  endg(b);
  // g23..g27: decode doubling with JIT G squarings
  push(b, DECA(0, off_Gr)); push(b, DECB(0, off_Gr)); endg(b);
  push(b, DECA(1, GPr)); push(b, DECB(1, GPr)); push(b, SQG(GPr,GPc,GQc,GQr)); endg(b);
  push(b, DECA(2, GQr)); push(b, DECB(2, GQr)); push(b, SQG(GQr,GQc,GPc,GPr)); endg(b);
  push(b, DECA(3, GPr)); push(b, DECB(3, GPr)); push(b, SQG(GPr,GPc,GQc,GQr)); endg(b);
  push(b, DECA(4, GQr)); endg(b);
  // g28: output p_t = 256 * (Wp h1_t) + bp
  { Op o=mko(); o.m_off=off_Wpr; o.rows=128; o.cols=2048; o.x1_off=off_S+512; o.x1_ks=1024;
    o.bias_off=off_bph; o.scale=RALPHAF; o.out32=1; push(b,o); }
  endg(b);
  b.p.nops=b.nops; b.p.ng=b.ng;
  return b.p;
}
static constexpr Plan h_plan = build_plan();
__device__ __constant__ Plan d_plan = h_plan;

// ---------------- sc0/sc1 (device-coherent, L1+L2-bypass) primitives ----------
__device__ inline void ldA_cc(const f16* pa, f16x8 (&ra)[8]) {
  asm volatile(
    "global_load_dwordx4 %0, %8, off sc0 sc1\n\t"
    "global_load_dwordx4 %1, %8, off offset:16 sc0 sc1\n\t"
    "global_load_dwordx4 %2, %8, off offset:32 sc0 sc1\n\t"
    "global_load_dwordx4 %3, %8, off offset:48 sc0 sc1\n\t"
    "global_load_dwordx4 %4, %8, off offset:64 sc0 sc1\n\t"
    "global_load_dwordx4 %5, %8, off offset:80 sc0 sc1\n\t"
    "global_load_dwordx4 %6, %8, off offset:96 sc0 sc1\n\t"
    "global_load_dwordx4 %7, %8, off offset:112 sc0 sc1\n\t"
    "s_waitcnt vmcnt(0)"
    : "=&v"(ra[0]), "=&v"(ra[1]), "=&v"(ra[2]), "=&v"(ra[3]),
      "=&v"(ra[4]), "=&v"(ra[5]), "=&v"(ra[6]), "=&v"(ra[7])
    : "v"(pa) : "memory");
}
__device__ inline void ldB_cc(const f16* pb, f16x8 (&rb)[4]) {
  asm volatile(
    "global_load_dwordx4 %0, %4, off sc0 sc1\n\t"
    "global_load_dwordx4 %1, %4, off offset:16 sc0 sc1\n\t"
    "global_load_dwordx4 %2, %4, off offset:32 sc0 sc1\n\t"
    "global_load_dwordx4 %3, %4, off offset:48 sc0 sc1\n\t"
    "s_waitcnt vmcnt(0)"
    : "=&v"(rb[0]), "=&v"(rb[1]), "=&v"(rb[2]), "=&v"(rb[3])
    : "v"(pb) : "memory");
}
__device__ inline f16x4 ld8_cc(const f16* p) {
  f16x4 r;
  asm volatile("global_load_dwordx2 %0, %1, off sc0 sc1\n\ts_waitcnt vmcnt(0)"
               : "=&v"(r) : "v"(p) : "memory");
  return r;
}
__device__ inline void st8_cc(f16* p, f16x4 v) {
  asm volatile("global_store_dwordx2 %0, %1, off sc0 sc1" :: "v"(p), "v"(v) : "memory");
}
__device__ inline void st2_cc(f16* p, f16 v) {
  unsigned d = __builtin_bit_cast(unsigned short, v);
  asm volatile("global_store_short %0, %1, off sc0 sc1" :: "v"(p), "v"(d) : "memory");
}
__device__ inline unsigned ld_u32_cc(const unsigned* p) {
  unsigned r;
  asm volatile("global_load_dword %0, %1, off sc0 sc1\n\ts_waitcnt vmcnt(0)"
               : "=&v"(r) : "v"(p) : "memory");
  return r;
}
__device__ inline void st_u32_cc(unsigned* p, unsigned v) {
  asm volatile("global_store_dword %0, %1, off sc0 sc1" :: "v"(p), "v"(v) : "memory");
}

// ---------------- fence-free grid barrier (relaxed atomics + LLC polls) -----
__device__ inline void grid_barrier(unsigned* ctrs, unsigned* flag, unsigned epoch) {
  __syncthreads();   // drains each wave's vmcnt (compiler emits full waitcnt)
  if (threadIdx.x == 0)
    __hip_atomic_fetch_add(&ctrs[(blockIdx.x & (NCTR-1))*32], 1u,
                           __ATOMIC_RELAXED, __HIP_MEMORY_SCOPE_AGENT);
  if (blockIdx.x == 0) {
    if (threadIdx.x < NCTR) {
      const unsigned tgt = epoch * (GRID / NCTR);
      while (ld_u32_cc(&ctrs[threadIdx.x*32]) < tgt)
        __builtin_amdgcn_s_sleep(2);
    }
    __syncthreads();
    if (threadIdx.x == 0) st_u32_cc(flag, epoch);
  } else if (threadIdx.x == 0) {
    while (ld_u32_cc(flag) < epoch)
      __builtin_amdgcn_s_sleep(2);
  }
  __syncthreads();
}

// ---------------- GEMM tile machinery (R7 structure + cc classification) ----
__device__ inline void chunk_srcs(const Op& o, const f16* w, int r0, int c0, int kc,
                                  const f16*& pa, const f16*& pb, bool& bcc) {
  const int tid = threadIdx.x;
  pa = w + o.m_off + (size_t)(r0 + (tid>>1)) * o.m_rstride + kc + (tid&1)*64;
  int C = c0 + (tid>>2);
  int xo, xks, xs1, xs2, xk;
  if (kc < o.k1) { xo=o.x1_off; xks=o.x1_ks; xs1=o.x1_s1; xs2=o.x1_s2; xk=kc; }
  else           { xo=o.x2_off; xks=o.x2_ks; xs1=o.x2_s1; xs2=o.x2_s2; xk=kc-o.k1; }
  int xcol = xs1*(C>>6) + (C&63) + xs2;
  pb = w + xo + (size_t)xcol*xks + xk + (tid&3)*32;
  bcc = dynb(xo);
}

__device__ inline void ld_regs(bool mcc, bool bcc, const f16* pa, const f16* pb,
                               f16x8 (&ra)[8], f16x8 (&rb)[4]) {
  if (mcc) ldA_cc(pa, ra);
  else {
#pragma unroll
    for (int i=0;i<8;++i) ra[i] = *(const f16x8*)(pa + i*8);
  }
  if (bcc) ldB_cc(pb, rb);
  else {
#pragma unroll
    for (int i=0;i<4;++i) rb[i] = *(const f16x8*)(pb + i*8);
  }
}

__device__ inline void st_lds(f16* lsA, f16* lsB, const f16x8 (&ra)[8], const f16x8 (&rb)[4]) {
  const int tid = threadIdx.x;
  f16* da = lsA + (tid>>1)*LDA + (tid&1)*64;
#pragma unroll
  for (int i=0;i<8;++i) *(f16x8*)(da + i*8) = ra[i];
  f16* db = lsB + (tid>>2)*LDA + (tid&3)*32;
#pragma unroll
  for (int i=0;i<4;++i) *(f16x8*)(db + i*8) = rb[i];
}

__device__ inline void mfma_lds(const f16* lsA, const f16* lsB, f32x4 (&acc)[4][2]) {
  const int tid = threadIdx.x, lane = tid & 63, wid = tid >> 6;
  const int wr = wid & 1, wc = wid >> 1;
  const int ko = (lane >> 4) * 8, rl = lane & 15;
#pragma unroll
  for (int kb = 0; kb < 4; ++kb) {
    f16x8 a[4], bb[2];
#pragma unroll
    for (int s = 0; s < 4; ++s)
      a[s] = *(const f16x8*)(lsA + (wr*64 + s*16 + rl) * LDA + kb*32 + ko);
#pragma unroll
    for (int c = 0; c < 2; ++c)
      bb[c] = *(const f16x8*)(lsB + (wc*32 + c*16 + rl) * LDA + kb*32 + ko);
#pragma unroll
    for (int s = 0; s < 4; ++s)
#pragma unroll
      for (int c = 0; c < 2; ++c)
        acc[s][c] = __builtin_amdgcn_mfma_f32_16x16x32_f16(a[s], bb[c], acc[s][c], 0, 0, 0);
  }
}

__device__ void run_tile(const Op& o, int local, f16* w, float* out, f16* lsA, f16* lsB) {
  int nct = o.cols >> 6;
  int rg = local / nct, ct = local - rg * nct;
  int r0 = rg << 7, c0 = ct << 6;
  const bool mcc = dynb(o.m_off);
  const bool addcc = dynb(o.add_off);
  const bool biascc = dynb(o.bias_off);
  f32x4 acc[4][2];
#pragma unroll
  for (int s=0;s<4;++s)
#pragma unroll
    for (int c=0;c<2;++c) acc[s][c] = f32x4{0.f,0.f,0.f,0.f};
  int nch = (o.k1 + o.k2) >> 7;
  if (nch > 0) {
    const f16 *pa, *pb; bool bcc;
    f16x8 ra[8], rb[4];
    chunk_srcs(o, w, r0, c0, 0, pa, pb, bcc);
    ld_regs(mcc, bcc, pa, pb, ra, rb);
    for (int c = 0; c < nch; ++c) {
      __syncthreads();
      st_lds(lsA, lsB, ra, rb);
      __syncthreads();
      if (c + 1 < nch) {
        chunk_srcs(o, w, r0, c0, (c+1)*128, pa, pb, bcc);
        ld_regs(mcc, bcc, pa, pb, ra, rb);
      }
      mfma_lds(lsA, lsB, acc);
    }
  }
  const int tid = threadIdx.x, lane = tid & 63, wid = tid >> 6;
  const int wr = wid & 1, wc = wid >> 1, rb2 = (lane >> 4) * 4, cl = lane & 15;
#pragma unroll
  for (int s = 0; s < 4; ++s) {
    int r = r0 + wr*64 + s*16 + rb2;
#pragma unroll
    for (int c = 0; c < 2; ++c) {
      int C = c0 + wc*32 + c*16 + cl;
      f32x4 v = acc[s][c];
      if (o.add_off >= 0) {
        int acol = o.add_s1 * (C>>6) + (C&63) + o.add_s2;
        const f16* ap = w + o.add_off + (size_t)acol * o.add_ks + r;
        f16x4 a4;
        if (addcc) a4 = ld8_cc(ap); else a4 = *(const f16x4*)ap;
        v[0]+=(float)a4[0]; v[1]+=(float)a4[1]; v[2]+=(float)a4[2]; v[3]+=(float)a4[3];
      }
      v[0]*=o.scale; v[1]*=o.scale; v[2]*=o.scale; v[3]*=o.scale;
      if (o.bias_off >= 0) {
        const f16* bp2 = w + o.bias_off + r;
        f16x4 b4;
        if (biascc) b4 = ld8_cc(bp2); else b4 = *(const f16x4*)bp2;
        v[0]+=(float)b4[0]; v[1]+=(float)b4[1]; v[2]+=(float)b4[2]; v[3]+=(float)b4[3];
      }
      if (o.y_off >= 0) {
        int ycol = o.y_s1 * (C>>6) + (C&63) + o.y_s2;
        f16* yp = w + o.y_off + (size_t)ycol * o.y_ks + r;
        f16x4 h; h[0]=(f16)v[0]; h[1]=(f16)v[1]; h[2]=(f16)v[2]; h[3]=(f16)v[3];
        st8_cc(yp, h);
      }
      if (o.yt_off >= 0) {
        f16* tp = w + o.yt_off;
        st2_cc(tp + (size_t)(r+0)*o.yt_rstride + C, (f16)v[0]);
        st2_cc(tp + (size_t)(r+1)*o.yt_rstride + C, (f16)v[1]);
        st2_cc(tp + (size_t)(r+2)*o.yt_rstride + C, (f16)v[2]);
        st2_cc(tp + (size_t)(r+3)*o.yt_rstride + C, (f16)v[3]);
      }
      if (o.out32) {
        float* op2 = out + (size_t)(C & 63) * (NF*DIN) + (size_t)(C >> 6) * DIN + r;
        op2[0]=v[0]; op2[1]=v[1]; op2[2]=v[2]; op2[3]=v[3];
      }
    }
  }
}

__global__ __launch_bounds__(256, 1) void rnn_main(f16* w, float* out) {
  __shared__ f16 lsA[128*LDA];
  __shared__ f16 lsB[64*LDA];
  unsigned* ctrs = (unsigned*)(w + off_ctr);
  unsigned* flag = ctrs + NCTR*32;
  const int wg = blockIdx.x;
  const int ng = d_plan.ng;
  for (int g = 0; g < ng; ++g) {
    int o0 = d_plan.gstart[g], o1 = d_plan.gstart[g+1];
    int gtot = d_plan.gtiles[g];
    for (int t = wg; t < gtot; t += GRID) {
      int oi = o0;
      while (oi + 1 < o1 && t >= d_plan.ops[oi+1].tile_base) ++oi;
      run_tile(d_plan.ops[oi], t - d_plan.ops[oi].tile_base, w, out, lsA, lsB);
    }
    grid_barrier(ctrs, flag, (unsigned)(g + 1));
  }
}

// ---------------- prep ----------------
__global__ void rnn_prep(f16* w, const float* X, const float* Wx0, const float* b0,
    const float* Wh0, const float* d0p, const float* Wx1, const float* b1,
    const float* Wh1, const float* d1p, const float* Wp, const float* bp)
{
  const float d0 = d0p[0], d1 = d1p[0];
  const long n0=512L*640, n1=512L*1024, n2=(long)SZ, n3=(long)SZ, n4=128L*512, n5=512L*128,
             n6=(long)SZ, n7=(long)SZ, n8=32768L*128, n9=512, n10=512, n11=512, n12=512,
             n13=128, n14=64L*128, n15=2048;
  const long total = n0+n1+n2+n3+n4+n5+n6+n7+n8+n9+n10+n11+n12+n13+n14+n15;
  for (long idx = (long)blockIdx.x*blockDim.x + threadIdx.x; idx < total;
       idx += (long)gridDim.x*blockDim.x) {
    long j = idx;
    if (j < n0) { int r=(int)(j/640), c=(int)(j%640);
      w[off_cat+j] = (f16)(c<512 ? d0*Wh0[(long)r*512+c] : Wx0[(long)r*128+(c-512)]); continue; }
    j -= n0;
    if (j < n1) { int r=(int)(j>>10), c=(int)(j&1023);
      w[off_catA1+j] = (f16)(c<512 ? d1*Wh1[(long)r*512+c] : Wx1[(long)r*512+(c-512)]); continue; }
    j -= n1;
    if (j < n2) { int c=(int)(j>>9), r=(int)(j&511); w[off_A0c+j] = (f16)(d0*Wh0[(long)r*512+c]); continue; }
    j -= n2;
    if (j < n3) { int c=(int)(j>>9), r=(int)(j&511); w[off_A1c+j] = (f16)(d1*Wh1[(long)r*512+c]); continue; }
    j -= n3;
    if (j < n4) { w[off_Wpr+j] = (f16)Wp[j]; continue; }
    j -= n4;
    if (j < n5) { int c=(int)(j>>7), k=(int)(j&127); w[off_Wpc+j] = (f16)Wp[(long)k*512+c]; continue; }
    j -= n5;
    if (j < n6) { int r=(int)(j>>9), c=(int)(j&511);
      w[off_Gr + (long)r*1024 + c] = (f16)(d0*Wh0[(long)r*512+c]); continue; }
    j -= n6;
    if (j < n7) { int c=(int)(j>>9), r=(int)(j&511);
      w[off_Gc + (long)c*1024 + r] = (f16)(d0*Wh0[(long)r*512+c]); continue; }
    j -= n7;
    if (j < n8) { int col=(int)(j>>7), d=(int)(j&127); int t=col>>6, bb=col&63;
      w[off_Xin+j] = (f16)X[((long)bb<<16) + ((long)t<<7) + d]; continue; }
    j -= n8;
    if (j < n9) { w[off_b0h+j] = (f16)b0[j]; continue; }  j -= n9;
    if (j < n10){ w[off_b1h+j] = (f16)b1[j]; continue; }  j -= n10;
    if (j < n11){ w[off_b0ah+j] = (f16)(ALPHAF*b0[j]); continue; }  j -= n11;
    if (j < n12){ w[off_b1ah+j] = (f16)(ALPHAF*b1[j]); continue; }  j -= n12;
    if (j < n13){ w[off_bph+j] = (f16)bp[j]; continue; }  j -= n13;
    if (j < n14){ int k=(int)(j&127); w[off_bpX+j] = (f16)bp[k]; continue; }  j -= n14;
    ((unsigned*)(w + off_ctr))[j] = 0u;
  }
}

extern "C" void kernel_launch(void* const* d_in, const int* in_sizes, int n_in,
                              void* d_out, int out_size, void* d_ws, size_t ws_size,
                              hipStream_t stream) {
  (void)in_sizes; (void)n_in; (void)out_size; (void)ws_size; // needs ~50 MB ws
  f16* w = (f16*)d_ws;
  hipLaunchKernelGGL(rnn_prep, dim3(2048), dim3(256), 0, stream,
      w,
      (const float*)d_in[0], (const float*)d_in[1], (const float*)d_in[2],
      (const float*)d_in[3], (const float*)d_in[4], (const float*)d_in[5],
      (const float*)d_in[6], (const float*)d_in[7], (const float*)d_in[8],
      (const float*)d_in[9], (const float*)d_in[10]);
  float* outp = (float*)d_out;
  void* kargs[] = { (void*)&w, (void*)&outp };
  hipLaunchCooperativeKernel((const void*)rnn_main, dim3(GRID), dim3(256), kargs, 0, stream);
}

// Round 9
// 661.081 us; speedup vs baseline: 3.8352x; 1.2849x over previous
//
#include <hip/hip_runtime.h>
#include <cstddef>

// MultiStepLinearRNN: 2-layer linear RNN, T=512 encode + F=32 decode.
// R9 = R8 (29-group plan, LLC sc0/sc1 state routing, fence-free barrier --
// PROVEN 849us) with ONE mechanism change: async 2-deep double-buffered
// register prefetch for all GEMM chunk loads (counted s_waitcnt vmcnt(12),
// T4 pattern) + batched async epilogue add/bias loads. Plan identical.
// fp16 MFMA 16x16x32, fp32 accum.

typedef _Float16 f16;
typedef _Float16 f16x8 __attribute__((ext_vector_type(8)));
typedef _Float16 f16x4 __attribute__((ext_vector_type(4)));
typedef float f32x4 __attribute__((ext_vector_type(4)));

#define GRID 256
#define NCTR 32
#define LDA  136     // LDS row stride in halves (128 + 8 pad)
#define ALPHAF 0.00390625f   // 2^-8 decode state pre-scale
#define RALPHAF 256.0f
#define DIN 128
#define NF 32

// ---------------- workspace layout (f16 element offsets) ----------------
constexpr int SZ = 512*512;
constexpr int off_cat   = 0;         // [512][640] = A0|Wx0 row-major   [static]
constexpr int off_catA1 = 327680;    // [512][1024] = A1|Wx1 row-major  [static]
constexpr int off_A0c   = 851968;    // A0 col-major [512c][512]        [static]
constexpr int off_A1c   = 1114112;   //                                 [static]
constexpr int off_Wpr   = 1376256;   // [128][512]                      [static]
constexpr int off_Wpc   = 1441792;   // [512c][128]                     [static]
constexpr int off_Gr    = 1507328;   // G row-major [1024][1024]        [dynamic from here]
constexpr int off_Gc    = 2555904;   // G col-major
constexpr int off_P0    = 3604480;   // A0 powers: 3 (row,col) slot pairs
constexpr int off_P1    = 5177344;   // A1 powers: 3 slot pairs
constexpr int GPr       = 6750208;   // G-power slot P row
constexpr int GPc       = 7798784;
constexpr int GQr       = 8847360;
constexpr int GQc       = 9895936;
constexpr int off_Xin   = 10944512;  // [32768c][128], col = t*64+b     [static]
constexpr int BA        = 15138816;  // 4 big buffers [4096c][512]      [dynamic]
constexpr int BB        = 17235968;
constexpr int BC        = 19333120;
constexpr int BD        = 21430272;
constexpr int off_S     = 23527424;  // decode states [2048c][1024]
constexpr int off_Dc    = 25624576;  // b_1 [64c][1024]
constexpr int off_Db    = 25690112;  // b_2,4,8,16: 4 x [64c][1024]
constexpr int off_b0h   = 25952256;  // [static from here]
constexpr int off_b1h   = 25952768;
constexpr int off_b0ah  = 25953280;
constexpr int off_b1ah  = 25953792;
constexpr int off_bph   = 25954304;
constexpr int off_bpX   = 25954432;  // bp replicated [64c][128]
constexpr int off_ctr   = 25962624;  // 2048 u32 barrier state
// end = 25966720 f16 = 49.5 MiB

// dynamic (kernel-rewritten) address classifier: these MUST use sc0sc1 ops
__host__ __device__ constexpr bool dynb(int off){
  return (off >= off_Gr && off < off_Xin) || (off >= BA && off < off_b0h);
}

constexpr int P0r(int s){ return off_P0 + s*524288; }
constexpr int P0c(int s){ return off_P0 + s*524288 + 262144; }
constexpr int P1r(int s){ return off_P1 + s*524288; }
constexpr int P1c(int s){ return off_P1 + s*524288 + 262144; }
constexpr int Bb(int k){ return k==0 ? off_Dc : off_Db + (k-1)*65536; }

// ---------------- op table ----------------
struct Op {
  int type;
  int m_off, m_rstride, rows, cols;
  int k1, x1_off, x1_ks, x1_s1, x1_s2;
  int k2, x2_off, x2_ks, x2_s1, x2_s2;
  int add_off, add_ks, add_s1, add_s2;
  int bias_off; float scale;
  int y_off, y_ks, y_s1, y_s2;
  int yt_off, yt_rstride;
  int out32, tile_base;
};
constexpr int MAXOPS = 80, MAXG = 32;
struct Plan { Op ops[MAXOPS]; int gstart[MAXG+1]; int gtiles[MAXG]; int nops, ng; };

constexpr Op mko() {
  Op o{};
  o.type=0; o.m_off=0; o.m_rstride=512; o.rows=512; o.cols=512;
  o.k1=512; o.x1_off=0; o.x1_ks=512; o.x1_s1=64; o.x1_s2=0;
  o.k2=0; o.x2_off=0; o.x2_ks=512; o.x2_s1=64; o.x2_s2=0;
  o.add_off=-1; o.add_ks=512; o.add_s1=64; o.add_s2=0;
  o.bias_off=-1; o.scale=1.0f;
  o.y_off=-1; o.y_ks=512; o.y_s1=64; o.y_s2=0;
  o.yt_off=-1; o.yt_rstride=512; o.out32=0; o.tile_base=0;
  return o;
}
constexpr int op_ntiles(const Op& o){ return (o.rows>>7)*(o.cols>>6); }

struct Builder { Plan p{}; int nops=0, ng=0, gtile=0; };
constexpr void push(Builder& b, Op o){ o.tile_base=b.gtile; b.gtile+=op_ntiles(o); b.p.ops[b.nops++]=o; }
constexpr void endg(Builder& b){ b.p.gtiles[b.ng]=b.gtile; b.ng++; b.p.gstart[b.ng]=b.nops; b.gtile=0; }

constexpr Op SQ2(int m,int mrs,int x1c,int yc,int yr){
  Op o=mko(); o.m_off=m; o.m_rstride=mrs; o.x1_off=x1c; o.y_off=yc; o.yt_off=yr; return o; }
constexpr Op SQG(int mr,int xc,int yc,int yr){
  Op o=mko(); o.rows=1024; o.cols=1024; o.k1=1024; o.m_off=mr; o.m_rstride=1024;
  o.x1_off=xc; o.x1_ks=1024; o.y_off=yc; o.y_ks=1024; o.yt_off=yr; o.yt_rstride=1024; return o; }
constexpr Op P2S(int s){
  Op o=mko(); o.cols=4096; o.bias_off=off_b0h;
  o.k2=128; o.x2_off=off_Xin; o.x2_ks=128; o.x2_s1=512; o.x2_s2=(s-1)*64;
  o.y_off=(s&1)?BA:BB;
  if (s==1){ o.m_off=off_cat+512; o.m_rstride=640; o.k1=0; }
  else { o.m_off=off_cat; o.m_rstride=640; o.k1=512; o.x1_off=(s&1)?BB:BA; }
  return o; }
constexpr Op HS(int s){
  Op o=mko(); o.m_off=off_cat; o.m_rstride=640; o.cols=4096;
  o.k1=512; o.x1_off=(s&1)?BC:BB;
  o.k2=128; o.x2_off=off_Xin; o.x2_ks=128; o.x2_s1=512; o.x2_s2=(s-1)*64;
  o.bias_off=off_b0h; o.y_off=(s&1)?BB:BC; return o; }
constexpr Op RS(int s){
  Op o=mko(); o.cols=4096; o.bias_off=off_b1h;
  if (s==1){ o.m_off=off_catA1+512; o.m_rstride=1024; o.k1=512; o.x1_off=BB; o.y_off=BD; }
  else { o.m_off=off_catA1; o.m_rstride=1024; o.k1=512; o.x1_off=(s&1)?BA:BD;
         o.k2=512; o.x2_off=(s&1)?BB:BC; o.x2_ks=512; o.x2_s1=64; o.x2_s2=0;
         o.y_off=(s&1)?BD:BA; }
  return o; }
constexpr Op SCAN(int m,int d,int inb,int outb){
  Op o=mko(); o.m_off=m; o.cols=4096-d*64; o.x1_off=inb;
  o.add_off=inb; o.add_s2=d*64; o.y_off=outb; o.y_s2=d*64; return o; }
constexpr Op SCOPY(int d,int inb,int outb){
  Op o=mko(); o.k1=0; o.cols=d*64; o.add_off=inb; o.y_off=outb; return o; }
constexpr Op FOLDL(int m,int cols,int inb,int outb){
  Op o=mko(); o.m_off=m; o.cols=cols; o.x1_off=inb; o.x1_s1=128;
  o.add_off=inb; o.add_s1=128; o.add_s2=64; o.y_off=outb; return o; }
constexpr Op DECA(int k,int moff){
  Op o=mko(); int m=1<<k;
  o.rows=1024; o.cols=m*64; o.k1=1024; o.m_off=moff; o.m_rstride=1024;
  o.x1_off=off_S; o.x1_ks=1024; o.bias_off=Bb(k);
  o.y_off=off_S; o.y_ks=1024; o.y_s2=m*64; return o; }
constexpr Op DECB(int k,int moff){
  Op o=mko(); o.rows=1024; o.cols=64; o.k1=1024; o.m_off=moff; o.m_rstride=1024;
  o.x1_off=Bb(k); o.x1_ks=1024; o.bias_off=Bb(k);
  o.y_off=Bb(k+1); o.y_ks=1024; return o; }

constexpr Plan build_plan() {
  Builder b{}; b.p.gstart[0]=0;
  // g0: A0^2, A1^2, E, c0, P2 s1
  push(b, SQ2(off_cat,640,off_A0c,P0c(0),P0r(0)));
  push(b, SQ2(off_catA1,1024,off_A1c,P1c(0),P1r(0)));
  { Op o=mko(); o.m_off=off_cat+512; o.m_rstride=640; o.k1=128; o.x1_off=off_Wpc; o.x1_ks=128;
    o.y_off=off_Gc+512*1024; o.y_ks=1024; o.yt_off=off_Gr+512; o.yt_rstride=1024; push(b,o); } // E
  { Op o=mko(); o.m_off=off_cat+512; o.m_rstride=640; o.k1=128; o.x1_off=off_bpX; o.x1_ks=128;
    o.cols=64; o.bias_off=off_b0ah; o.scale=ALPHAF; o.y_off=off_Dc; o.y_ks=1024; push(b,o); } // c0
  push(b, P2S(1)); endg(b);
  // g1: A0^4, A1^4, F10, c1, P2 s2
  push(b, SQ2(P0r(0),512,P0c(0),P0c(1),P0r(1)));
  push(b, SQ2(P1r(0),512,P1c(0),P1c(1),P1r(1)));
  { Op o=mko(); o.m_off=off_catA1+512; o.m_rstride=1024; o.x1_off=off_A0c;
    o.y_off=off_Gc+512; o.y_ks=1024; o.yt_off=off_Gr+512*1024; o.yt_rstride=1024; push(b,o); } // F10
  { Op o=mko(); o.m_off=off_catA1+512; o.m_rstride=1024; o.x1_off=off_Dc; o.x1_ks=1024;
    o.cols=64; o.bias_off=off_b1ah; o.y_off=off_Dc+512; o.y_ks=1024; push(b,o); } // c1
  push(b, P2S(2)); endg(b);
  // g2: A0^8, A1^8, F11, P2 s3
  push(b, SQ2(P0r(1),512,P0c(1),P0c(2),P0r(2)));
  push(b, SQ2(P1r(1),512,P1c(1),P1c(2),P1r(2)));
  { Op o=mko(); o.m_off=off_catA1+512; o.m_rstride=1024; o.x1_off=off_Gc+512*1024; o.x1_ks=1024;
    o.add_off=off_A1c; o.y_off=off_Gc+512*1024+512; o.y_ks=1024;
    o.yt_off=off_Gr+512*1024+512; o.yt_rstride=1024; push(b,o); } // F11 = Wx1 E + A1
  push(b, P2S(3)); endg(b);
  // g3: A0^16, A1^16, P2 s4
  push(b, SQ2(P0r(2),512,P0c(2),P0c(0),P0r(0)));
  push(b, SQ2(P1r(2),512,P1c(2),P1c(0),P1r(0)));
  push(b, P2S(4)); endg(b);
  // g4: A0^32, A1^32, P2 s5
  push(b, SQ2(P0r(0),512,P0c(0),P0c(1),P0r(1)));
  push(b, SQ2(P1r(0),512,P1c(0),P1c(1),P1r(1)));
  push(b, P2S(5)); endg(b);
  // g5: P2 s6 + G^2
  push(b, P2S(6));
  push(b, SQG(off_Gr, off_Gc, GPc, GPr)); endg(b);
  // g6,g7: P2 s7, s8   (g = BB)
  push(b, P2S(7)); endg(b);
  push(b, P2S(8)); endg(b);
  // g8..g10: scan levels (A0^8, A0^16, A0^32) -> final in BA
  push(b, SCAN(P0r(2), 1, BB, BA)); push(b, SCOPY(1, BB, BA)); endg(b);
  push(b, SCAN(P0r(0), 2, BA, BB)); push(b, SCOPY(2, BA, BB)); endg(b);
  push(b, SCAN(P0r(1), 4, BB, BA)); push(b, SCOPY(4, BB, BA)); endg(b);
  // g11: h1 (shifted chunk-start read) -> BB
  { Op o=mko(); o.m_off=off_cat; o.m_rstride=640; o.cols=4032; o.k1=512; o.x1_off=BA;
    o.k2=128; o.x2_off=off_Xin; o.x2_ks=128; o.x2_s1=512; o.x2_s2=512;
    o.bias_off=off_b0h; o.y_off=BB; o.y_s2=64; push(b,o); }
  { Op o=mko(); o.m_off=off_cat+512; o.m_rstride=640; o.cols=64; o.k1=0;
    o.k2=128; o.x2_off=off_Xin; o.x2_ks=128; o.x2_s1=512; o.x2_s2=0;
    o.bias_off=off_b0h; o.y_off=BB; push(b,o); }
  endg(b);
  // g12..g18: {h(s+1), r(s)} for s=1..7
  for (int s=1; s<=7; ++s){ push(b, HS(s+1)); push(b, RS(s)); endg(b); }
  // g19: r8 + h0_final -> S top
  push(b, RS(8));
  { Op o=mko(); o.k1=0; o.cols=64; o.add_off=BC; o.add_s2=4032; o.scale=ALPHAF;
    o.y_off=off_S; o.y_ks=1024; push(b,o); }
  endg(b);
  // g20,g21: fold l0 (A1^8), l1 (A1^16)
  push(b, FOLDL(P1r(2), 2048, BA, BB)); endg(b);
  push(b, FOLDL(P1r(0), 1024, BB, BC)); endg(b);
  // g22: h1_final = v15 + A1^32 v14 -> S bottom
  { Op o=mko(); o.m_off=P1r(1); o.cols=64; o.x1_off=BC; o.x1_s2=896;
    o.add_off=BC; o.add_s2=960; o.scale=ALPHAF;
    o.y_off=off_S+512; o.y_ks=1024; push(b,o); }
  endg(b);
  // g23..g27: decode doubling with JIT G squarings
  push(b, DECA(0, off_Gr)); push(b, DECB(0, off_Gr)); endg(b);
  push(b, DECA(1, GPr)); push(b, DECB(1, GPr)); push(b, SQG(GPr,GPc,GQc,GQr)); endg(b);
  push(b, DECA(2, GQr)); push(b, DECB(2, GQr)); push(b, SQG(GQr,GQc,GPc,GPr)); endg(b);
  push(b, DECA(3, GPr)); push(b, DECB(3, GPr)); push(b, SQG(GPr,GPc,GQc,GQr)); endg(b);
  push(b, DECA(4, GQr)); endg(b);
  // g28: output p_t = 256 * (Wp h1_t) + bp
  { Op o=mko(); o.m_off=off_Wpr; o.rows=128; o.cols=2048; o.x1_off=off_S+512; o.x1_ks=1024;
    o.bias_off=off_bph; o.scale=RALPHAF; o.out32=1; push(b,o); }
  endg(b);
  b.p.nops=b.nops; b.p.ng=b.ng;
  return b.p;
}
static constexpr Plan h_plan = build_plan();
__device__ __constant__ Plan d_plan = h_plan;

// ---------------- async load primitives (NO trailing waitcnt) --------------
__device__ inline void issueA(const f16* pa, f16x8 (&ra)[8], bool cc) {
  if (cc)
    asm volatile(
      "global_load_dwordx4 %0, %8, off sc0 sc1\n\t"
      "global_load_dwordx4 %1, %8, off offset:16 sc0 sc1\n\t"
      "global_load_dwordx4 %2, %8, off offset:32 sc0 sc1\n\t"
      "global_load_dwordx4 %3, %8, off offset:48 sc0 sc1\n\t"
      "global_load_dwordx4 %4, %8, off offset:64 sc0 sc1\n\t"
      "global_load_dwordx4 %5, %8, off offset:80 sc0 sc1\n\t"
      "global_load_dwordx4 %6, %8, off offset:96 sc0 sc1\n\t"
      "global_load_dwordx4 %7, %8, off offset:112 sc0 sc1"
      : "=&v"(ra[0]), "=&v"(ra[1]), "=&v"(ra[2]), "=&v"(ra[3]),
        "=&v"(ra[4]), "=&v"(ra[5]), "=&v"(ra[6]), "=&v"(ra[7])
      : "v"(pa) : "memory");
  else
    asm volatile(
      "global_load_dwordx4 %0, %8, off\n\t"
      "global_load_dwordx4 %1, %8, off offset:16\n\t"
      "global_load_dwordx4 %2, %8, off offset:32\n\t"
      "global_load_dwordx4 %3, %8, off offset:48\n\t"
      "global_load_dwordx4 %4, %8, off offset:64\n\t"
      "global_load_dwordx4 %5, %8, off offset:80\n\t"
      "global_load_dwordx4 %6, %8, off offset:96\n\t"
      "global_load_dwordx4 %7, %8, off offset:112"
      : "=&v"(ra[0]), "=&v"(ra[1]), "=&v"(ra[2]), "=&v"(ra[3]),
        "=&v"(ra[4]), "=&v"(ra[5]), "=&v"(ra[6]), "=&v"(ra[7])
      : "v"(pa) : "memory");
}
__device__ inline void issueB(const f16* pb, f16x8 (&rb)[4], bool cc) {
  if (cc)
    asm volatile(
      "global_load_dwordx4 %0, %4, off sc0 sc1\n\t"
      "global_load_dwordx4 %1, %4, off offset:16 sc0 sc1\n\t"
      "global_load_dwordx4 %2, %4, off offset:32 sc0 sc1\n\t"
      "global_load_dwordx4 %3, %4, off offset:48 sc0 sc1"
      : "=&v"(rb[0]), "=&v"(rb[1]), "=&v"(rb[2]), "=&v"(rb[3])
      : "v"(pb) : "memory");
  else
    asm volatile(
      "global_load_dwordx4 %0, %4, off\n\t"
      "global_load_dwordx4 %1, %4, off offset:16\n\t"
      "global_load_dwordx4 %2, %4, off offset:32\n\t"
      "global_load_dwordx4 %3, %4, off offset:48"
      : "=&v"(rb[0]), "=&v"(rb[1]), "=&v"(rb[2]), "=&v"(rb[3])
      : "v"(pb) : "memory");
}
__device__ inline void issue_ld8(const f16* p, f16x4& r) {
  asm volatile("global_load_dwordx2 %0, %1, off sc0 sc1"
               : "=&v"(r) : "v"(p) : "memory");
}
__device__ inline void st8_cc(f16* p, f16x4 v) {
  asm volatile("global_store_dwordx2 %0, %1, off sc0 sc1" :: "v"(p), "v"(v) : "memory");
}
__device__ inline void st2_cc(f16* p, f16 v) {
  unsigned d = __builtin_bit_cast(unsigned short, v);
  asm volatile("global_store_short %0, %1, off sc0 sc1" :: "v"(p), "v"(d) : "memory");
}
__device__ inline unsigned ld_u32_cc(const unsigned* p) {
  unsigned r;
  asm volatile("global_load_dword %0, %1, off sc0 sc1\n\ts_waitcnt vmcnt(0)"
               : "=&v"(r) : "v"(p) : "memory");
  return r;
}
__device__ inline void st_u32_cc(unsigned* p, unsigned v) {
  asm volatile("global_store_dword %0, %1, off sc0 sc1" :: "v"(p), "v"(v) : "memory");
}

// ---------------- fence-free grid barrier (relaxed atomics + LLC polls) -----
__device__ inline void grid_barrier(unsigned* ctrs, unsigned* flag, unsigned epoch) {
  __syncthreads();
  if (threadIdx.x == 0)
    __hip_atomic_fetch_add(&ctrs[(blockIdx.x & (NCTR-1))*32], 1u,
                           __ATOMIC_RELAXED, __HIP_MEMORY_SCOPE_AGENT);
  if (blockIdx.x == 0) {
    if (threadIdx.x < NCTR) {
      const unsigned tgt = epoch * (GRID / NCTR);
      while (ld_u32_cc(&ctrs[threadIdx.x*32]) < tgt)
        __builtin_amdgcn_s_sleep(2);
    }
    __syncthreads();
    if (threadIdx.x == 0) st_u32_cc(flag, epoch);
  } else if (threadIdx.x == 0) {
    while (ld_u32_cc(flag) < epoch)
      __builtin_amdgcn_s_sleep(2);
  }
  __syncthreads();
}

// ---------------- GEMM tile machinery ----------------
__device__ inline void chunk_srcs(const Op& o, const f16* w, int r0, int c0, int kc,
                                  const f16*& pa, const f16*& pb, bool& bcc) {
  const int tid = threadIdx.x;
  pa = w + o.m_off + (size_t)(r0 + (tid>>1)) * o.m_rstride + kc + (tid&1)*64;
  int C = c0 + (tid>>2);
  int xo, xks, xs1, xs2, xk;
  if (kc < o.k1) { xo=o.x1_off; xks=o.x1_ks; xs1=o.x1_s1; xs2=o.x1_s2; xk=kc; }
  else           { xo=o.x2_off; xks=o.x2_ks; xs1=o.x2_s1; xs2=o.x2_s2; xk=kc-o.k1; }
  int xcol = xs1*(C>>6) + (C&63) + xs2;
  pb = w + xo + (size_t)xcol*xks + xk + (tid&3)*32;
  bcc = dynb(xo);
}

__device__ inline void st_lds(f16* lsA, f16* lsB, const f16x8 (&ra)[8], const f16x8 (&rb)[4]) {
  const int tid = threadIdx.x;
  f16* da = lsA + (tid>>1)*LDA + (tid&1)*64;
#pragma unroll
  for (int i=0;i<8;++i) *(f16x8*)(da + i*8) = ra[i];
  f16* db = lsB + (tid>>2)*LDA + (tid&3)*32;
#pragma unroll
  for (int i=0;i<4;++i) *(f16x8*)(db + i*8) = rb[i];
}

__device__ inline void mfma_lds(const f16* lsA, const f16* lsB, f32x4 (&acc)[4][2]) {
  const int tid = threadIdx.x, lane = tid & 63, wid = tid >> 6;
  const int wr = wid & 1, wc = wid >> 1;
  const int ko = (lane >> 4) * 8, rl = lane & 15;
#pragma unroll
  for (int kb = 0; kb < 4; ++kb) {
    f16x8 a[4], bb[2];
#pragma unroll
    for (int s = 0; s < 4; ++s)
      a[s] = *(const f16x8*)(lsA + (wr*64 + s*16 + rl) * LDA + kb*32 + ko);
#pragma unroll
    for (int c = 0; c < 2; ++c)
      bb[c] = *(const f16x8*)(lsB + (wc*32 + c*16 + rl) * LDA + kb*32 + ko);
#pragma unroll
    for (int s = 0; s < 4; ++s)
#pragma unroll
      for (int c = 0; c < 2; ++c)
        acc[s][c] = __builtin_amdgcn_mfma_f32_16x16x32_f16(a[s], bb[c], acc[s][c], 0, 0, 0);
  }
}

// One chunk step: wait for this chunk's loads (chunk c+1 stays in flight:
// vmcnt(12) = 12 loads of the NEWER chunk outstanding; m135 oldest-first),
// stage to LDS, issue chunk c+2 into the just-freed buffer, MFMA.
#define CH_STEP(c_, raX, rbX)                                                  \
  do {                                                                         \
    __syncthreads();                                                           \
    if ((c_) < nch - 1) asm volatile("s_waitcnt vmcnt(12)" ::: "memory");      \
    else                asm volatile("s_waitcnt vmcnt(0)"  ::: "memory");      \
    st_lds(lsA, lsB, raX, rbX);                                                \
    __syncthreads();                                                           \
    if ((c_) + 2 < nch) {                                                      \
      chunk_srcs(o, w, r0, c0, ((c_)+2)*128, pa, pb, bcc);                     \
      issueA(pa, raX, mcc); issueB(pb, rbX, bcc);                              \
    }                                                                          \
    mfma_lds(lsA, lsB, acc);                                                   \
  } while (0)

__device__ void run_tile(const Op& o, int local, f16* w, float* out, f16* lsA, f16* lsB) {
  int nct = o.cols >> 6;
  int rg = local / nct, ct = local - rg * nct;
  int r0 = rg << 7, c0 = ct << 6;
  const bool mcc = dynb(o.m_off);
  const bool addcc = dynb(o.add_off);
  const bool biascc = dynb(o.bias_off);
  f32x4 acc[4][2];
#pragma unroll
  for (int s=0;s<4;++s)
#pragma unroll
    for (int c=0;c<2;++c) acc[s][c] = f32x4{0.f,0.f,0.f,0.f};
  int nch = (o.k1 + o.k2) >> 7;
  if (nch > 0) {
    const f16 *pa, *pb; bool bcc;
    f16x8 ra0[8], rb0[4], ra1[8], rb1[4];
    chunk_srcs(o, w, r0, c0, 0, pa, pb, bcc);
    issueA(pa, ra0, mcc); issueB(pb, rb0, bcc);
    if (nch > 1) {
      chunk_srcs(o, w, r0, c0, 128, pa, pb, bcc);
      issueA(pa, ra1, mcc); issueB(pb, rb1, bcc);
    }
    for (int c = 0; c < nch; c += 2) {
      CH_STEP(c, ra0, rb0);
      if (c + 1 < nch) CH_STEP(c+1, ra1, rb1);
    }
  }
  const int tid = threadIdx.x, lane = tid & 63, wid = tid >> 6;
  const int wr = wid & 1, wc = wid >> 1, rb2 = (lane >> 4) * 4, cl = lane & 15;
  // ---- batched epilogue operand loads (issue all async, wait once) ----
  f16x4 addv[4][2], biasv[4];
  bool pend = false;
  if (o.add_off >= 0) {
#pragma unroll
    for (int s = 0; s < 4; ++s) {
      int r = r0 + wr*64 + s*16 + rb2;
#pragma unroll
      for (int c = 0; c < 2; ++c) {
        int C = c0 + wc*32 + c*16 + cl;
        int acol = o.add_s1 * (C>>6) + (C&63) + o.add_s2;
        const f16* ap = w + o.add_off + (size_t)acol * o.add_ks + r;
        if (addcc) { issue_ld8(ap, addv[s][c]); pend = true; }
        else addv[s][c] = *(const f16x4*)ap;
      }
    }
  }
  if (o.bias_off >= 0) {
#pragma unroll
    for (int s = 0; s < 4; ++s) {
      int r = r0 + wr*64 + s*16 + rb2;
      const f16* bp2 = w + o.bias_off + r;
      if (biascc) { issue_ld8(bp2, biasv[s]); pend = true; }
      else biasv[s] = *(const f16x4*)bp2;
    }
  }
  if (pend) asm volatile("s_waitcnt vmcnt(0)" ::: "memory");
#pragma unroll
  for (int s = 0; s < 4; ++s) {
    int r = r0 + wr*64 + s*16 + rb2;
#pragma unroll
    for (int c = 0; c < 2; ++c) {
      int C = c0 + wc*32 + c*16 + cl;
      f32x4 v = acc[s][c];
      if (o.add_off >= 0) {
        v[0]+=(float)addv[s][c][0]; v[1]+=(float)addv[s][c][1];
        v[2]+=(float)addv[s][c][2]; v[3]+=(float)addv[s][c][3];
      }
      v[0]*=o.scale; v[1]*=o.scale; v[2]*=o.scale; v[3]*=o.scale;
      if (o.bias_off >= 0) {
        v[0]+=(float)biasv[s][0]; v[1]+=(float)biasv[s][1];
        v[2]+=(float)biasv[s][2]; v[3]+=(float)biasv[s][3];
      }
      if (o.y_off >= 0) {
        int ycol = o.y_s1 * (C>>6) + (C&63) + o.y_s2;
        f16* yp = w + o.y_off + (size_t)ycol * o.y_ks + r;
        f16x4 h; h[0]=(f16)v[0]; h[1]=(f16)v[1]; h[2]=(f16)v[2]; h[3]=(f16)v[3];
        st8_cc(yp, h);
      }
      if (o.yt_off >= 0) {
        f16* tp = w + o.yt_off;
        st2_cc(tp + (size_t)(r+0)*o.yt_rstride + C, (f16)v[0]);
        st2_cc(tp + (size_t)(r+1)*o.yt_rstride + C, (f16)v[1]);
        st2_cc(tp + (size_t)(r+2)*o.yt_rstride + C, (f16)v[2]);
        st2_cc(tp + (size_t)(r+3)*o.yt_rstride + C, (f16)v[3]);
      }
      if (o.out32) {
        float* op2 = out + (size_t)(C & 63) * (NF*DIN) + (size_t)(C >> 6) * DIN + r;
        op2[0]=v[0]; op2[1]=v[1]; op2[2]=v[2]; op2[3]=v[3];
      }
    }
  }
}

__global__ __launch_bounds__(256, 1) void rnn_main(f16* w, float* out) {
  __shared__ f16 lsA[128*LDA];
  __shared__ f16 lsB[64*LDA];
  unsigned* ctrs = (unsigned*)(w + off_ctr);
  unsigned* flag = ctrs + NCTR*32;
  const int wg = blockIdx.x;
  const int ng = d_plan.ng;
  for (int g = 0; g < ng; ++g) {
    int o0 = d_plan.gstart[g], o1 = d_plan.gstart[g+1];
    int gtot = d_plan.gtiles[g];
    for (int t = wg; t < gtot; t += GRID) {
      int oi = o0;
      while (oi + 1 < o1 && t >= d_plan.ops[oi+1].tile_base) ++oi;
      run_tile(d_plan.ops[oi], t - d_plan.ops[oi].tile_base, w, out, lsA, lsB);
    }
    grid_barrier(ctrs, flag, (unsigned)(g + 1));
  }
}

// ---------------- prep ----------------
__global__ void rnn_prep(f16* w, const float* X, const float* Wx0, const float* b0,
    const float* Wh0, const float* d0p, const float* Wx1, const float* b1,
    const float* Wh1, const float* d1p, const float* Wp, const float* bp)
{
  const float d0 = d0p[0], d1 = d1p[0];
  const long n0=512L*640, n1=512L*1024, n2=(long)SZ, n3=(long)SZ, n4=128L*512, n5=512L*128,
             n6=(long)SZ, n7=(long)SZ, n8=32768L*128, n9=512, n10=512, n11=512, n12=512,
             n13=128, n14=64L*128, n15=2048;
  const long total = n0+n1+n2+n3+n4+n5+n6+n7+n8+n9+n10+n11+n12+n13+n14+n15;
  for (long idx = (long)blockIdx.x*blockDim.x + threadIdx.x; idx < total;
       idx += (long)gridDim.x*blockDim.x) {
    long j = idx;
    if (j < n0) { int r=(int)(j/640), c=(int)(j%640);
      w[off_cat+j] = (f16)(c<512 ? d0*Wh0[(long)r*512+c] : Wx0[(long)r*128+(c-512)]); continue; }
    j -= n0;
    if (j < n1) { int r=(int)(j>>10), c=(int)(j&1023);
      w[off_catA1+j] = (f16)(c<512 ? d1*Wh1[(long)r*512+c] : Wx1[(long)r*512+(c-512)]); continue; }
    j -= n1;
    if (j < n2) { int c=(int)(j>>9), r=(int)(j&511); w[off_A0c+j] = (f16)(d0*Wh0[(long)r*512+c]); continue; }
    j -= n2;
    if (j < n3) { int c=(int)(j>>9), r=(int)(j&511); w[off_A1c+j] = (f16)(d1*Wh1[(long)r*512+c]); continue; }
    j -= n3;
    if (j < n4) { w[off_Wpr+j] = (f16)Wp[j]; continue; }
    j -= n4;
    if (j < n5) { int c=(int)(j>>7), k=(int)(j&127); w[off_Wpc+j] = (f16)Wp[(long)k*512+c]; continue; }
    j -= n5;
    if (j < n6) { int r=(int)(j>>9), c=(int)(j&511);
      w[off_Gr + (long)r*1024 + c] = (f16)(d0*Wh0[(long)r*512+c]); continue; }
    j -= n6;
    if (j < n7) { int c=(int)(j>>9), r=(int)(j&511);
      w[off_Gc + (long)c*1024 + r] = (f16)(d0*Wh0[(long)r*512+c]); continue; }
    j -= n7;
    if (j < n8) { int col=(int)(j>>7), d=(int)(j&127); int t=col>>6, bb=col&63;
      w[off_Xin+j] = (f16)X[((long)bb<<16) + ((long)t<<7) + d]; continue; }
    j -= n8;
    if (j < n9) { w[off_b0h+j] = (f16)b0[j]; continue; }  j -= n9;
    if (j < n10){ w[off_b1h+j] = (f16)b1[j]; continue; }  j -= n10;
    if (j < n11){ w[off_b0ah+j] = (f16)(ALPHAF*b0[j]); continue; }  j -= n11;
    if (j < n12){ w[off_b1ah+j] = (f16)(ALPHAF*b1[j]); continue; }  j -= n12;
    if (j < n13){ w[off_bph+j] = (f16)bp[j]; continue; }  j -= n13;
    if (j < n14){ int k=(int)(j&127); w[off_bpX+j] = (f16)bp[k]; continue; }  j -= n14;
    ((unsigned*)(w + off_ctr))[j] = 0u;
  }
}

extern "C" void kernel_launch(void* const* d_in, const int* in_sizes, int n_in,
                              void* d_out, int out_size, void* d_ws, size_t ws_size,
                              hipStream_t stream) {
  (void)in_sizes; (void)n_in; (void)out_size; (void)ws_size; // needs ~50 MB ws
  f16* w = (f16*)d_ws;
  hipLaunchKernelGGL(rnn_prep, dim3(2048), dim3(256), 0, stream,
      w,
      (const float*)d_in[0], (const float*)d_in[1], (const float*)d_in[2],
      (const float*)d_in[3], (const float*)d_in[4], (const float*)d_in[5],
      (const float*)d_in[6], (const float*)d_in[7], (const float*)d_in[8],
      (const float*)d_in[9], (const float*)d_in[10]);
  float* outp = (float*)d_out;
  void* kargs[] = { (void*)&w, (void*)&outp };
  hipLaunchCooperativeKernel((const void*)rnn_main, dim3(GRID), dim3(256), kargs, 0, stream);
}

// Round 10
// 553.852 us; speedup vs baseline: 4.5777x; 1.1936x over previous
//
#include <hip/hip_runtime.h>
#include <cstddef>

// MultiStepLinearRNN: 2-layer linear RNN, T=512 encode + F=32 decode.
// R10 = R9 (29-group plan, LLC sc0/sc1 routing, fence-free barrier, async
// 2-deep prefetch -- PROVEN 661us) with ONE mechanism change: 64x64 tiles
// (512 tiles per heavy group) + GRID 512 = 2 blocks/CU for TLP latency
// hiding. Plan/numerics byte-identical. Host falls back to GRID 256 if
// 2-block occupancy unavailable. fp16 MFMA 16x16x32, fp32 accum.

typedef _Float16 f16;
typedef _Float16 f16x8 __attribute__((ext_vector_type(8)));
typedef _Float16 f16x4 __attribute__((ext_vector_type(4)));
typedef float f32x4 __attribute__((ext_vector_type(4)));

#define NCTR 32
#define LDA  136     // LDS row stride in halves (128 + 8 pad)
#define ALPHAF 0.00390625f   // 2^-8 decode state pre-scale
#define RALPHAF 256.0f
#define DIN 128
#define NF 32

// ---------------- workspace layout (f16 element offsets) ----------------
constexpr int SZ = 512*512;
constexpr int off_cat   = 0;         // [512][640] = A0|Wx0 row-major   [static]
constexpr int off_catA1 = 327680;    // [512][1024] = A1|Wx1 row-major  [static]
constexpr int off_A0c   = 851968;    // A0 col-major [512c][512]        [static]
constexpr int off_A1c   = 1114112;   //                                 [static]
constexpr int off_Wpr   = 1376256;   // [128][512]                      [static]
constexpr int off_Wpc   = 1441792;   // [512c][128]                     [static]
constexpr int off_Gr    = 1507328;   // G row-major [1024][1024]        [dynamic from here]
constexpr int off_Gc    = 2555904;   // G col-major
constexpr int off_P0    = 3604480;   // A0 powers: 3 (row,col) slot pairs
constexpr int off_P1    = 5177344;   // A1 powers: 3 slot pairs
constexpr int GPr       = 6750208;   // G-power slot P row
constexpr int GPc       = 7798784;
constexpr int GQr       = 8847360;
constexpr int GQc       = 9895936;
constexpr int off_Xin   = 10944512;  // [32768c][128], col = t*64+b     [static]
constexpr int BA        = 15138816;  // 4 big buffers [4096c][512]      [dynamic]
constexpr int BB        = 17235968;
constexpr int BC        = 19333120;
constexpr int BD        = 21430272;
constexpr int off_S     = 23527424;  // decode states [2048c][1024]
constexpr int off_Dc    = 25624576;  // b_1 [64c][1024]
constexpr int off_Db    = 25690112;  // b_2,4,8,16: 4 x [64c][1024]
constexpr int off_b0h   = 25952256;  // [static from here]
constexpr int off_b1h   = 25952768;
constexpr int off_b0ah  = 25953280;
constexpr int off_b1ah  = 25953792;
constexpr int off_bph   = 25954304;
constexpr int off_bpX   = 25954432;  // bp replicated [64c][128]
constexpr int off_ctr   = 25962624;  // 2048 u32 barrier state
// end = 25966720 f16 = 49.5 MiB

// dynamic (kernel-rewritten) address classifier: these MUST use sc0sc1 ops
__host__ __device__ constexpr bool dynb(int off){
  return (off >= off_Gr && off < off_Xin) || (off >= BA && off < off_b0h);
}

constexpr int P0r(int s){ return off_P0 + s*524288; }
constexpr int P0c(int s){ return off_P0 + s*524288 + 262144; }
constexpr int P1r(int s){ return off_P1 + s*524288; }
constexpr int P1c(int s){ return off_P1 + s*524288 + 262144; }
constexpr int Bb(int k){ return k==0 ? off_Dc : off_Db + (k-1)*65536; }

// ---------------- op table ----------------
struct Op {
  int type;
  int m_off, m_rstride, rows, cols;
  int k1, x1_off, x1_ks, x1_s1, x1_s2;
  int k2, x2_off, x2_ks, x2_s1, x2_s2;
  int add_off, add_ks, add_s1, add_s2;
  int bias_off; float scale;
  int y_off, y_ks, y_s1, y_s2;
  int yt_off, yt_rstride;
  int out32, tile_base;
};
constexpr int MAXOPS = 80, MAXG = 32;
struct Plan { Op ops[MAXOPS]; int gstart[MAXG+1]; int gtiles[MAXG]; int nops, ng; };

constexpr Op mko() {
  Op o{};
  o.type=0; o.m_off=0; o.m_rstride=512; o.rows=512; o.cols=512;
  o.k1=512; o.x1_off=0; o.x1_ks=512; o.x1_s1=64; o.x1_s2=0;
  o.k2=0; o.x2_off=0; o.x2_ks=512; o.x2_s1=64; o.x2_s2=0;
  o.add_off=-1; o.add_ks=512; o.add_s1=64; o.add_s2=0;
  o.bias_off=-1; o.scale=1.0f;
  o.y_off=-1; o.y_ks=512; o.y_s1=64; o.y_s2=0;
  o.yt_off=-1; o.yt_rstride=512; o.out32=0; o.tile_base=0;
  return o;
}
// 64x64 tiles now
constexpr int op_ntiles(const Op& o){ return (o.rows>>6)*(o.cols>>6); }

struct Builder { Plan p{}; int nops=0, ng=0, gtile=0; };
constexpr void push(Builder& b, Op o){ o.tile_base=b.gtile; b.gtile+=op_ntiles(o); b.p.ops[b.nops++]=o; }
constexpr void endg(Builder& b){ b.p.gtiles[b.ng]=b.gtile; b.ng++; b.p.gstart[b.ng]=b.nops; b.gtile=0; }

constexpr Op SQ2(int m,int mrs,int x1c,int yc,int yr){
  Op o=mko(); o.m_off=m; o.m_rstride=mrs; o.x1_off=x1c; o.y_off=yc; o.yt_off=yr; return o; }
constexpr Op SQG(int mr,int xc,int yc,int yr){
  Op o=mko(); o.rows=1024; o.cols=1024; o.k1=1024; o.m_off=mr; o.m_rstride=1024;
  o.x1_off=xc; o.x1_ks=1024; o.y_off=yc; o.y_ks=1024; o.yt_off=yr; o.yt_rstride=1024; return o; }
constexpr Op P2S(int s){
  Op o=mko(); o.cols=4096; o.bias_off=off_b0h;
  o.k2=128; o.x2_off=off_Xin; o.x2_ks=128; o.x2_s1=512; o.x2_s2=(s-1)*64;
  o.y_off=(s&1)?BA:BB;
  if (s==1){ o.m_off=off_cat+512; o.m_rstride=640; o.k1=0; }
  else { o.m_off=off_cat; o.m_rstride=640; o.k1=512; o.x1_off=(s&1)?BB:BA; }
  return o; }
constexpr Op HS(int s){
  Op o=mko(); o.m_off=off_cat; o.m_rstride=640; o.cols=4096;
  o.k1=512; o.x1_off=(s&1)?BC:BB;
  o.k2=128; o.x2_off=off_Xin; o.x2_ks=128; o.x2_s1=512; o.x2_s2=(s-1)*64;
  o.bias_off=off_b0h; o.y_off=(s&1)?BB:BC; return o; }
constexpr Op RS(int s){
  Op o=mko(); o.cols=4096; o.bias_off=off_b1h;
  if (s==1){ o.m_off=off_catA1+512; o.m_rstride=1024; o.k1=512; o.x1_off=BB; o.y_off=BD; }
  else { o.m_off=off_catA1; o.m_rstride=1024; o.k1=512; o.x1_off=(s&1)?BA:BD;
         o.k2=512; o.x2_off=(s&1)?BB:BC; o.x2_ks=512; o.x2_s1=64; o.x2_s2=0;
         o.y_off=(s&1)?BD:BA; }
  return o; }
constexpr Op SCAN(int m,int d,int inb,int outb){
  Op o=mko(); o.m_off=m; o.cols=4096-d*64; o.x1_off=inb;
  o.add_off=inb; o.add_s2=d*64; o.y_off=outb; o.y_s2=d*64; return o; }
constexpr Op SCOPY(int d,int inb,int outb){
  Op o=mko(); o.k1=0; o.cols=d*64; o.add_off=inb; o.y_off=outb; return o; }
constexpr Op FOLDL(int m,int cols,int inb,int outb){
  Op o=mko(); o.m_off=m; o.cols=cols; o.x1_off=inb; o.x1_s1=128;
  o.add_off=inb; o.add_s1=128; o.add_s2=64; o.y_off=outb; return o; }
constexpr Op DECA(int k,int moff){
  Op o=mko(); int m=1<<k;
  o.rows=1024; o.cols=m*64; o.k1=1024; o.m_off=moff; o.m_rstride=1024;
  o.x1_off=off_S; o.x1_ks=1024; o.bias_off=Bb(k);
  o.y_off=off_S; o.y_ks=1024; o.y_s2=m*64; return o; }
constexpr Op DECB(int k,int moff){
  Op o=mko(); o.rows=1024; o.cols=64; o.k1=1024; o.m_off=moff; o.m_rstride=1024;
  o.x1_off=Bb(k); o.x1_ks=1024; o.bias_off=Bb(k);
  o.y_off=Bb(k+1); o.y_ks=1024; return o; }

constexpr Plan build_plan() {
  Builder b{}; b.p.gstart[0]=0;
  // g0: A0^2, A1^2, E, c0, P2 s1
  push(b, SQ2(off_cat,640,off_A0c,P0c(0),P0r(0)));
  push(b, SQ2(off_catA1,1024,off_A1c,P1c(0),P1r(0)));
  { Op o=mko(); o.m_off=off_cat+512; o.m_rstride=640; o.k1=128; o.x1_off=off_Wpc; o.x1_ks=128;
    o.y_off=off_Gc+512*1024; o.y_ks=1024; o.yt_off=off_Gr+512; o.yt_rstride=1024; push(b,o); } // E
  { Op o=mko(); o.m_off=off_cat+512; o.m_rstride=640; o.k1=128; o.x1_off=off_bpX; o.x1_ks=128;
    o.cols=64; o.bias_off=off_b0ah; o.scale=ALPHAF; o.y_off=off_Dc; o.y_ks=1024; push(b,o); } // c0
  push(b, P2S(1)); endg(b);
  // g1: A0^4, A1^4, F10, c1, P2 s2
  push(b, SQ2(P0r(0),512,P0c(0),P0c(1),P0r(1)));
  push(b, SQ2(P1r(0),512,P1c(0),P1c(1),P1r(1)));
  { Op o=mko(); o.m_off=off_catA1+512; o.m_rstride=1024; o.x1_off=off_A0c;
    o.y_off=off_Gc+512; o.y_ks=1024; o.yt_off=off_Gr+512*1024; o.yt_rstride=1024; push(b,o); } // F10
  { Op o=mko(); o.m_off=off_catA1+512; o.m_rstride=1024; o.x1_off=off_Dc; o.x1_ks=1024;
    o.cols=64; o.bias_off=off_b1ah; o.y_off=off_Dc+512; o.y_ks=1024; push(b,o); } // c1
  push(b, P2S(2)); endg(b);
  // g2: A0^8, A1^8, F11, P2 s3
  push(b, SQ2(P0r(1),512,P0c(1),P0c(2),P0r(2)));
  push(b, SQ2(P1r(1),512,P1c(1),P1c(2),P1r(2)));
  { Op o=mko(); o.m_off=off_catA1+512; o.m_rstride=1024; o.x1_off=off_Gc+512*1024; o.x1_ks=1024;
    o.add_off=off_A1c; o.y_off=off_Gc+512*1024+512; o.y_ks=1024;
    o.yt_off=off_Gr+512*1024+512; o.yt_rstride=1024; push(b,o); } // F11 = Wx1 E + A1
  push(b, P2S(3)); endg(b);
  // g3: A0^16, A1^16, P2 s4
  push(b, SQ2(P0r(2),512,P0c(2),P0c(0),P0r(0)));
  push(b, SQ2(P1r(2),512,P1c(2),P1c(0),P1r(0)));
  push(b, P2S(4)); endg(b);
  // g4: A0^32, A1^32, P2 s5
  push(b, SQ2(P0r(0),512,P0c(0),P0c(1),P0r(1)));
  push(b, SQ2(P1r(0),512,P1c(0),P1c(1),P1r(1)));
  push(b, P2S(5)); endg(b);
  // g5: P2 s6 + G^2
  push(b, P2S(6));
  push(b, SQG(off_Gr, off_Gc, GPc, GPr)); endg(b);
  // g6,g7: P2 s7, s8   (g = BB)
  push(b, P2S(7)); endg(b);
  push(b, P2S(8)); endg(b);
  // g8..g10: scan levels (A0^8, A0^16, A0^32) -> final in BA
  push(b, SCAN(P0r(2), 1, BB, BA)); push(b, SCOPY(1, BB, BA)); endg(b);
  push(b, SCAN(P0r(0), 2, BA, BB)); push(b, SCOPY(2, BA, BB)); endg(b);
  push(b, SCAN(P0r(1), 4, BB, BA)); push(b, SCOPY(4, BB, BA)); endg(b);
  // g11: h1 (shifted chunk-start read) -> BB
  { Op o=mko(); o.m_off=off_cat; o.m_rstride=640; o.cols=4032; o.k1=512; o.x1_off=BA;
    o.k2=128; o.x2_off=off_Xin; o.x2_ks=128; o.x2_s1=512; o.x2_s2=512;
    o.bias_off=off_b0h; o.y_off=BB; o.y_s2=64; push(b,o); }
  { Op o=mko(); o.m_off=off_cat+512; o.m_rstride=640; o.cols=64; o.k1=0;
    o.k2=128; o.x2_off=off_Xin; o.x2_ks=128; o.x2_s1=512; o.x2_s2=0;
    o.bias_off=off_b0h; o.y_off=BB; push(b,o); }
  endg(b);
  // g12..g18: {h(s+1), r(s)} for s=1..7
  for (int s=1; s<=7; ++s){ push(b, HS(s+1)); push(b, RS(s)); endg(b); }
  // g19: r8 + h0_final -> S top
  push(b, RS(8));
  { Op o=mko(); o.k1=0; o.cols=64; o.add_off=BC; o.add_s2=4032; o.scale=ALPHAF;
    o.y_off=off_S; o.y_ks=1024; push(b,o); }
  endg(b);
  // g20,g21: fold l0 (A1^8), l1 (A1^16)
  push(b, FOLDL(P1r(2), 2048, BA, BB)); endg(b);
  push(b, FOLDL(P1r(0), 1024, BB, BC)); endg(b);
  // g22: h1_final = v15 + A1^32 v14 -> S bottom
  { Op o=mko(); o.m_off=P1r(1); o.cols=64; o.x1_off=BC; o.x1_s2=896;
    o.add_off=BC; o.add_s2=960; o.scale=ALPHAF;
    o.y_off=off_S+512; o.y_ks=1024; push(b,o); }
  endg(b);
  // g23..g27: decode doubling with JIT G squarings
  push(b, DECA(0, off_Gr)); push(b, DECB(0, off_Gr)); endg(b);
  push(b, DECA(1, GPr)); push(b, DECB(1, GPr)); push(b, SQG(GPr,GPc,GQc,GQr)); endg(b);
  push(b, DECA(2, GQr)); push(b, DECB(2, GQr)); push(b, SQG(GQr,GQc,GPc,GPr)); endg(b);
  push(b, DECA(3, GPr)); push(b, DECB(3, GPr)); push(b, SQG(GPr,GPc,GQc,GQr)); endg(b);
  push(b, DECA(4, GQr)); endg(b);
  // g28: output p_t = 256 * (Wp h1_t) + bp
  { Op o=mko(); o.m_off=off_Wpr; o.rows=128; o.cols=2048; o.x1_off=off_S+512; o.x1_ks=1024;
    o.bias_off=off_bph; o.scale=RALPHAF; o.out32=1; push(b,o); }
  endg(b);
  b.p.nops=b.nops; b.p.ng=b.ng;
  return b.p;
}
static constexpr Plan h_plan = build_plan();
__device__ __constant__ Plan d_plan = h_plan;

// ---------------- async load primitives (NO trailing waitcnt) --------------
// 4 x dwordx4 = 64B per thread (A rows and B cols are both 64B/thread now)
__device__ inline void issue4(const f16* p, f16x8 (&r)[4], bool cc) {
  if (cc)
    asm volatile(
      "global_load_dwordx4 %0, %4, off sc0 sc1\n\t"
      "global_load_dwordx4 %1, %4, off offset:16 sc0 sc1\n\t"
      "global_load_dwordx4 %2, %4, off offset:32 sc0 sc1\n\t"
      "global_load_dwordx4 %3, %4, off offset:48 sc0 sc1"
      : "=&v"(r[0]), "=&v"(r[1]), "=&v"(r[2]), "=&v"(r[3])
      : "v"(p) : "memory");
  else
    asm volatile(
      "global_load_dwordx4 %0, %4, off\n\t"
      "global_load_dwordx4 %1, %4, off offset:16\n\t"
      "global_load_dwordx4 %2, %4, off offset:32\n\t"
      "global_load_dwordx4 %3, %4, off offset:48"
      : "=&v"(r[0]), "=&v"(r[1]), "=&v"(r[2]), "=&v"(r[3])
      : "v"(p) : "memory");
}
__device__ inline void issue_ld8(const f16* p, f16x4& r) {
  asm volatile("global_load_dwordx2 %0, %1, off sc0 sc1"
               : "=&v"(r) : "v"(p) : "memory");
}
__device__ inline void st8_cc(f16* p, f16x4 v) {
  asm volatile("global_store_dwordx2 %0, %1, off sc0 sc1" :: "v"(p), "v"(v) : "memory");
}
__device__ inline void st2_cc(f16* p, f16 v) {
  unsigned d = __builtin_bit_cast(unsigned short, v);
  asm volatile("global_store_short %0, %1, off sc0 sc1" :: "v"(p), "v"(d) : "memory");
}
__device__ inline unsigned ld_u32_cc(const unsigned* p) {
  unsigned r;
  asm volatile("global_load_dword %0, %1, off sc0 sc1\n\ts_waitcnt vmcnt(0)"
               : "=&v"(r) : "v"(p) : "memory");
  return r;
}
__device__ inline void st_u32_cc(unsigned* p, unsigned v) {
  asm volatile("global_store_dword %0, %1, off sc0 sc1" :: "v"(p), "v"(v) : "memory");
}

// ---------------- fence-free grid barrier (gridDim-agnostic) ----------------
__device__ inline void grid_barrier(unsigned* ctrs, unsigned* flag, unsigned epoch) {
  __syncthreads();
  if (threadIdx.x == 0)
    __hip_atomic_fetch_add(&ctrs[(blockIdx.x & (NCTR-1))*32], 1u,
                           __ATOMIC_RELAXED, __HIP_MEMORY_SCOPE_AGENT);
  if (blockIdx.x == 0) {
    if (threadIdx.x < NCTR) {
      const unsigned tgt = epoch * (gridDim.x / NCTR);
      while (ld_u32_cc(&ctrs[threadIdx.x*32]) < tgt)
        __builtin_amdgcn_s_sleep(2);
    }
    __syncthreads();
    if (threadIdx.x == 0) st_u32_cc(flag, epoch);
  } else if (threadIdx.x == 0) {
    while (ld_u32_cc(flag) < epoch)
      __builtin_amdgcn_s_sleep(2);
  }
  __syncthreads();
}

// ---------------- GEMM tile machinery (64x64 tiles) ----------------
__device__ inline void chunk_srcs(const Op& o, const f16* w, int r0, int c0, int kc,
                                  const f16*& pa, const f16*& pb, bool& bcc) {
  const int tid = threadIdx.x;
  pa = w + o.m_off + (size_t)(r0 + (tid>>2)) * o.m_rstride + kc + (tid&3)*32;
  int C = c0 + (tid>>2);
  int xo, xks, xs1, xs2, xk;
  if (kc < o.k1) { xo=o.x1_off; xks=o.x1_ks; xs1=o.x1_s1; xs2=o.x1_s2; xk=kc; }
  else           { xo=o.x2_off; xks=o.x2_ks; xs1=o.x2_s1; xs2=o.x2_s2; xk=kc-o.k1; }
  int xcol = xs1*(C>>6) + (C&63) + xs2;
  pb = w + xo + (size_t)xcol*xks + xk + (tid&3)*32;
  bcc = dynb(xo);
}

__device__ inline void st_lds(f16* lsA, f16* lsB, const f16x8 (&ra)[4], const f16x8 (&rb)[4]) {
  const int tid = threadIdx.x;
  f16* da = lsA + (tid>>2)*LDA + (tid&3)*32;
#pragma unroll
  for (int i=0;i<4;++i) *(f16x8*)(da + i*8) = ra[i];
  f16* db = lsB + (tid>>2)*LDA + (tid&3)*32;
#pragma unroll
  for (int i=0;i<4;++i) *(f16x8*)(db + i*8) = rb[i];
}

__device__ inline void mfma_lds(const f16* lsA, const f16* lsB, f32x4 (&acc)[4]) {
  const int tid = threadIdx.x, lane = tid & 63, wid = tid >> 6;
  const int ko = (lane >> 4) * 8, rl = lane & 15;
#pragma unroll
  for (int kb = 0; kb < 4; ++kb) {
    f16x8 a = *(const f16x8*)(lsA + (wid*16 + rl) * LDA + kb*32 + ko);
#pragma unroll
    for (int n = 0; n < 4; ++n) {
      f16x8 bb = *(const f16x8*)(lsB + (n*16 + rl) * LDA + kb*32 + ko);
      acc[n] = __builtin_amdgcn_mfma_f32_16x16x32_f16(a, bb, acc[n], 0, 0, 0);
    }
  }
}

// One chunk step: wait for this chunk's 8 loads (next chunk's 8 in flight),
// stage to LDS, issue chunk c+2 into the freed buffer, MFMA.
#define CH_STEP(c_, raX, rbX)                                                  \
  do {                                                                         \
    __syncthreads();                                                           \
    if ((c_) < nch - 1) asm volatile("s_waitcnt vmcnt(8)" ::: "memory");       \
    else                asm volatile("s_waitcnt vmcnt(0)" ::: "memory");       \
    st_lds(lsA, lsB, raX, rbX);                                                \
    __syncthreads();                                                           \
    if ((c_) + 2 < nch) {                                                      \
      chunk_srcs(o, w, r0, c0, ((c_)+2)*128, pa, pb, bcc);                     \
      issue4(pa, raX, mcc); issue4(pb, rbX, bcc);                              \
    }                                                                          \
    mfma_lds(lsA, lsB, acc);                                                   \
  } while (0)

__device__ void run_tile(const Op& o, int local, f16* w, float* out, f16* lsA, f16* lsB) {
  int nct = o.cols >> 6;
  int rg = local / nct, ct = local - rg * nct;
  int r0 = rg << 6, c0 = ct << 6;
  const bool mcc = dynb(o.m_off);
  const bool addcc = dynb(o.add_off);
  const bool biascc = dynb(o.bias_off);
  f32x4 acc[4];
#pragma unroll
  for (int n=0;n<4;++n) acc[n] = f32x4{0.f,0.f,0.f,0.f};
  int nch = (o.k1 + o.k2) >> 7;
  if (nch > 0) {
    const f16 *pa, *pb; bool bcc;
    f16x8 ra0[4], rb0[4], ra1[4], rb1[4];
    chunk_srcs(o, w, r0, c0, 0, pa, pb, bcc);
    issue4(pa, ra0, mcc); issue4(pb, rb0, bcc);
    if (nch > 1) {
      chunk_srcs(o, w, r0, c0, 128, pa, pb, bcc);
      issue4(pa, ra1, mcc); issue4(pb, rb1, bcc);
    }
    for (int c = 0; c < nch; c += 2) {
      CH_STEP(c, ra0, rb0);
      if (c + 1 < nch) CH_STEP(c+1, ra1, rb1);
    }
  }
  const int tid = threadIdx.x, lane = tid & 63, wid = tid >> 6;
  const int q4 = (lane >> 4) * 4, cl = lane & 15;
  const int r = r0 + wid*16 + q4;
  // ---- batched epilogue operand loads (issue all async, wait once) ----
  f16x4 addv[4], biasv;
  bool pend = false;
  if (o.add_off >= 0) {
#pragma unroll
    for (int n = 0; n < 4; ++n) {
      int C = c0 + n*16 + cl;
      int acol = o.add_s1 * (C>>6) + (C&63) + o.add_s2;
      const f16* ap = w + o.add_off + (size_t)acol * o.add_ks + r;
      if (addcc) { issue_ld8(ap, addv[n]); pend = true; }
      else addv[n] = *(const f16x4*)ap;
    }
  }
  if (o.bias_off >= 0) {
    const f16* bp2 = w + o.bias_off + r;
    if (biascc) { issue_ld8(bp2, biasv); pend = true; }
    else biasv = *(const f16x4*)bp2;
  }
  if (pend) asm volatile("s_waitcnt vmcnt(0)" ::: "memory");
#pragma unroll
  for (int n = 0; n < 4; ++n) {
    int C = c0 + n*16 + cl;
    f32x4 v = acc[n];
    if (o.add_off >= 0) {
      v[0]+=(float)addv[n][0]; v[1]+=(float)addv[n][1];
      v[2]+=(float)addv[n][2]; v[3]+=(float)addv[n][3];
    }
    v[0]*=o.scale; v[1]*=o.scale; v[2]*=o.scale; v[3]*=o.scale;
    if (o.bias_off >= 0) {
      v[0]+=(float)biasv[0]; v[1]+=(float)biasv[1];
      v[2]+=(float)biasv[2]; v[3]+=(float)biasv[3];
    }
    if (o.y_off >= 0) {
      int ycol = o.y_s1 * (C>>6) + (C&63) + o.y_s2;
      f16* yp = w + o.y_off + (size_t)ycol * o.y_ks + r;
      f16x4 h; h[0]=(f16)v[0]; h[1]=(f16)v[1]; h[2]=(f16)v[2]; h[3]=(f16)v[3];
      st8_cc(yp, h);
    }
    if (o.yt_off >= 0) {
      f16* tp = w + o.yt_off;
      st2_cc(tp + (size_t)(r+0)*o.yt_rstride + C, (f16)v[0]);
      st2_cc(tp + (size_t)(r+1)*o.yt_rstride + C, (f16)v[1]);
      st2_cc(tp + (size_t)(r+2)*o.yt_rstride + C, (f16)v[2]);
      st2_cc(tp + (size_t)(r+3)*o.yt_rstride + C, (f16)v[3]);
    }
    if (o.out32) {
      float* op2 = out + (size_t)(C & 63) * (NF*DIN) + (size_t)(C >> 6) * DIN + r;
      op2[0]=v[0]; op2[1]=v[1]; op2[2]=v[2]; op2[3]=v[3];
    }
  }
}

__global__ __launch_bounds__(256, 2) void rnn_main(f16* w, float* out) {
  __shared__ f16 lsA[64*LDA];
  __shared__ f16 lsB[64*LDA];
  unsigned* ctrs = (unsigned*)(w + off_ctr);
  unsigned* flag = ctrs + NCTR*32;
  const int wg = blockIdx.x;
  const int stride = gridDim.x;
  const int ng = d_plan.ng;
  for (int g = 0; g < ng; ++g) {
    int o0 = d_plan.gstart[g], o1 = d_plan.gstart[g+1];
    int gtot = d_plan.gtiles[g];
    for (int t = wg; t < gtot; t += stride) {
      int oi = o0;
      while (oi + 1 < o1 && t >= d_plan.ops[oi+1].tile_base) ++oi;
      run_tile(d_plan.ops[oi], t - d_plan.ops[oi].tile_base, w, out, lsA, lsB);
    }
    grid_barrier(ctrs, flag, (unsigned)(g + 1));
  }
}

// ---------------- prep ----------------
__global__ void rnn_prep(f16* w, const float* X, const float* Wx0, const float* b0,
    const float* Wh0, const float* d0p, const float* Wx1, const float* b1,
    const float* Wh1, const float* d1p, const float* Wp, const float* bp)
{
  const float d0 = d0p[0], d1 = d1p[0];
  const long n0=512L*640, n1=512L*1024, n2=(long)SZ, n3=(long)SZ, n4=128L*512, n5=512L*128,
             n6=(long)SZ, n7=(long)SZ, n8=32768L*128, n9=512, n10=512, n11=512, n12=512,
             n13=128, n14=64L*128, n15=2048;
  const long total = n0+n1+n2+n3+n4+n5+n6+n7+n8+n9+n10+n11+n12+n13+n14+n15;
  for (long idx = (long)blockIdx.x*blockDim.x + threadIdx.x; idx < total;
       idx += (long)gridDim.x*blockDim.x) {
    long j = idx;
    if (j < n0) { int r=(int)(j/640), c=(int)(j%640);
      w[off_cat+j] = (f16)(c<512 ? d0*Wh0[(long)r*512+c] : Wx0[(long)r*128+(c-512)]); continue; }
    j -= n0;
    if (j < n1) { int r=(int)(j>>10), c=(int)(j&1023);
      w[off_catA1+j] = (f16)(c<512 ? d1*Wh1[(long)r*512+c] : Wx1[(long)r*512+(c-512)]); continue; }
    j -= n1;
    if (j < n2) { int c=(int)(j>>9), r=(int)(j&511); w[off_A0c+j] = (f16)(d0*Wh0[(long)r*512+c]); continue; }
    j -= n2;
    if (j < n3) { int c=(int)(j>>9), r=(int)(j&511); w[off_A1c+j] = (f16)(d1*Wh1[(long)r*512+c]); continue; }
    j -= n3;
    if (j < n4) { w[off_Wpr+j] = (f16)Wp[j]; continue; }
    j -= n4;
    if (j < n5) { int c=(int)(j>>7), k=(int)(j&127); w[off_Wpc+j] = (f16)Wp[(long)k*512+c]; continue; }
    j -= n5;
    if (j < n6) { int r=(int)(j>>9), c=(int)(j&511);
      w[off_Gr + (long)r*1024 + c] = (f16)(d0*Wh0[(long)r*512+c]); continue; }
    j -= n6;
    if (j < n7) { int c=(int)(j>>9), r=(int)(j&511);
      w[off_Gc + (long)c*1024 + r] = (f16)(d0*Wh0[(long)r*512+c]); continue; }
    j -= n7;
    if (j < n8) { int col=(int)(j>>7), d=(int)(j&127); int t=col>>6, bb=col&63;
      w[off_Xin+j] = (f16)X[((long)bb<<16) + ((long)t<<7) + d]; continue; }
    j -= n8;
    if (j < n9) { w[off_b0h+j] = (f16)b0[j]; continue; }  j -= n9;
    if (j < n10){ w[off_b1h+j] = (f16)b1[j]; continue; }  j -= n10;
    if (j < n11){ w[off_b0ah+j] = (f16)(ALPHAF*b0[j]); continue; }  j -= n11;
    if (j < n12){ w[off_b1ah+j] = (f16)(ALPHAF*b1[j]); continue; }  j -= n12;
    if (j < n13){ w[off_bph+j] = (f16)bp[j]; continue; }  j -= n13;
    if (j < n14){ int k=(int)(j&127); w[off_bpX+j] = (f16)bp[k]; continue; }  j -= n14;
    ((unsigned*)(w + off_ctr))[j] = 0u;
  }
}

extern "C" void kernel_launch(void* const* d_in, const int* in_sizes, int n_in,
                              void* d_out, int out_size, void* d_ws, size_t ws_size,
                              hipStream_t stream) {
  (void)in_sizes; (void)n_in; (void)out_size; (void)ws_size; // needs ~50 MB ws
  f16* w = (f16*)d_ws;
  hipLaunchKernelGGL(rnn_prep, dim3(2048), dim3(256), 0, stream,
      w,
      (const float*)d_in[0], (const float*)d_in[1], (const float*)d_in[2],
      (const float*)d_in[3], (const float*)d_in[4], (const float*)d_in[5],
      (const float*)d_in[6], (const float*)d_in[7], (const float*)d_in[8],
      (const float*)d_in[9], (const float*)d_in[10]);
  float* outp = (float*)d_out;
  void* kargs[] = { (void*)&w, (void*)&outp };
  // deterministic grid selection: 2 blocks/CU if occupancy allows, else 1
  int nb = 0;
  hipError_t qe = hipOccupancyMaxActiveBlocksPerMultiprocessor(
      &nb, (const void*)rnn_main, 256, 0);
  int grid = (qe == hipSuccess && nb >= 2) ? 512 : 256;
  hipError_t le = hipLaunchCooperativeKernel((const void*)rnn_main, dim3(grid),
                                             dim3(256), kargs, 0, stream);
  if (le != hipSuccess && grid == 512) {
    hipLaunchCooperativeKernel((const void*)rnn_main, dim3(256),
                               dim3(256), kargs, 0, stream);
  }
}